// Round 5
// baseline (1320.507 us; speedup 1.0000x reference)
//
#include <hip/hip_runtime.h>
#include <math.h>

#define MI 512
#define NPT 8192
#define JIT 1e-6f
#define LOG2PI 1.8378770664093453f

// ws float offsets
#define OFF_A     0         // 512x512 Kuu -> L (lower; diag blocks left unfactored, never read)
#define OFF_LINV  262144    // 512x512 Linv^T (LT[r][c] = Linv[c][r])
#define OFF_QS    524288    // 512x512 q_sqrt
#define OFF_QC    786432    // 512x512 q_cov (symmetric)
#define OFF_DINV  1048576   // 8 x 64x64 diag-block inverses
#define OFF_W     1081344   // 512  w = Linv^T q_mu
#define OFF_PART  1081856   // 512 block partial ell sums
#define OFF_FLAGS 1082368   // [0..7] chol panel done, [8..71] linv tiles

#define FMA16(ACC,a0,a1,a2,a3,b0,b1,b2,b3) \
  ACC[0][0]+=a0*b0; ACC[0][1]+=a0*b1; ACC[0][2]+=a0*b2; ACC[0][3]+=a0*b3; \
  ACC[1][0]+=a1*b0; ACC[1][1]+=a1*b1; ACC[1][2]+=a1*b2; ACC[1][3]+=a1*b3; \
  ACC[2][0]+=a2*b0; ACC[2][1]+=a2*b1; ACC[2][2]+=a2*b2; ACC[2][3]+=a2*b3; \
  ACC[3][0]+=a3*b0; ACC[3][1]+=a3*b1; ACC[3][2]+=a3*b2; ACC[3][3]+=a3*b3;

__device__ __forceinline__ void wait_flag(unsigned* f, int tid) {
  if (tid == 0) {
    while (__hip_atomic_load(f, __ATOMIC_RELAXED, __HIP_MEMORY_SCOPE_AGENT) == 0)
      __builtin_amdgcn_s_sleep(2);
    __builtin_amdgcn_fence(__ATOMIC_ACQUIRE, "agent");
  }
  __syncthreads();
}
__device__ __forceinline__ void raise_flag(unsigned* f, int tid) {
  __syncthreads();
  if (tid == 0) {
    __builtin_amdgcn_fence(__ATOMIC_RELEASE, "agent");
    __hip_atomic_store(f, 1u, __ATOMIC_RELAXED, __HIP_MEMORY_SCOPE_AGENT);
  }
}

// ---------------------------------------------------------------- prep
__global__ __launch_bounds__(256) void k_prep(const float* __restrict__ Z,
    const float* __restrict__ qlv, const float* __restrict__ lsP,
    const float* __restrict__ osP, float* __restrict__ ws) {
  int u = blockIdx.x*256 + threadIdx.x;
  if (blockIdx.x == 0 && threadIdx.x < 128)
    ((unsigned*)(ws + OFF_FLAGS))[threadIdx.x] = 0u;
  float ls = lsP[0], os = osP[0];
  float ils2 = 1.0f/(ls*ls);
  if (u < MI*MI) {
    int i = u >> 9, j = u & 511;
    float4 a0 = *(const float4*)(Z + i*8);
    float4 a1 = *(const float4*)(Z + i*8 + 4);
    float4 b0 = *(const float4*)(Z + j*8);
    float4 b1 = *(const float4*)(Z + j*8 + 4);
    float d0=a0.x-b0.x, d1=a0.y-b0.y, d2=a0.z-b0.z, d3=a0.w-b0.w;
    float d4=a1.x-b1.x, d5=a1.y-b1.y, d6=a1.z-b1.z, d7=a1.w-b1.w;
    float sq = d0*d0+d1*d1+d2*d2+d3*d3+d4*d4+d5*d5+d6*d6+d7*d7;
    float v = os*__expf(-0.5f*ils2*sq);
    if (i==j) v += JIT;
    ws[OFF_A + u] = v;
  } else {
    int w2 = u - MI*MI;
    if (w2 < MI*MI) {
      int i = w2 >> 9, j = w2 & 511;
      ws[OFF_QS + w2] = (j <= i) ? __expf(0.5f*qlv[w2]) : 0.0f;
    }
  }
}

// ------------------------------------------------- O = X Y^T + adiag*I (K=512)
__global__ __launch_bounds__(256) void k_gemm_nt(const float* __restrict__ X,
    const float* __restrict__ Y, float* __restrict__ O, float adiag) {
  __shared__ float Xs[64][20], Ys[64][20];
  int tid = threadIdx.x;
  int bi = blockIdx.y, bj = blockIdx.x;
  int ty4 = (tid >> 4)*4, tx4 = (tid & 15)*4;
  int lrow = tid >> 2, lc4 = (tid & 3)*4;
  float acc[4][4] = {{0.f}};
  for (int kc = 0; kc < 512; kc += 16) {
    float4 xa = *(const float4*)(X + (bi*64+lrow)*512 + kc + lc4);
    float4 ya = *(const float4*)(Y + (bj*64+lrow)*512 + kc + lc4);
    Xs[lrow][lc4+0]=xa.x; Xs[lrow][lc4+1]=xa.y; Xs[lrow][lc4+2]=xa.z; Xs[lrow][lc4+3]=xa.w;
    Ys[lrow][lc4+0]=ya.x; Ys[lrow][lc4+1]=ya.y; Ys[lrow][lc4+2]=ya.z; Ys[lrow][lc4+3]=ya.w;
    __syncthreads();
    #pragma unroll
    for (int kk = 0; kk < 16; ++kk) {
      float a0=Xs[ty4+0][kk],a1=Xs[ty4+1][kk],a2=Xs[ty4+2][kk],a3=Xs[ty4+3][kk];
      float b0=Ys[tx4+0][kk],b1=Ys[tx4+1][kk],b2=Ys[tx4+2][kk],b3=Ys[tx4+3][kk];
      FMA16(acc,a0,a1,a2,a3,b0,b1,b2,b3)
    }
    __syncthreads();
  }
  #pragma unroll
  for (int u = 0; u < 4; ++u)
    #pragma unroll
    for (int v = 0; v < 4; ++v) {
      int gi = bi*64+ty4+u, gj = bj*64+tx4+v;
      float o = acc[u][v]; if (gi==gj) o += adiag;
      O[gi*512+gj] = o;
    }
}

// ------------- fused Cholesky: block b owns row-block b; flag[p] = panel p done
__global__ __launch_bounds__(256) void k_chol_all(float* __restrict__ ws) {
  float* A = ws + OFF_A;
  float* DINV = ws + OFF_DINV;
  unsigned* flg = (unsigned*)(ws + OFF_FLAGS);
  __shared__ float LkR[64][20], LkC[64][20];
  __shared__ float Ds[64][65];
  __shared__ float Vs[64][65];
  __shared__ float rD[64];
  int tid = threadIdx.x, b = blockIdx.x;
  int ty4 = (tid >> 4)*4, tx4 = (tid & 15)*4;
  int lrow = tid >> 2, lc4 = (tid & 3)*4;
  int Rb = b*64;

  // ---- sub-panel columns p = 0..b-1 (left-looking)
  for (int p = 0; p < b; ++p) {
    int base = p*64;
    wait_flag(&flg[p], tid);
    float acc[4][4] = {{0.f}};
    for (int kc = 0; kc < base; kc += 16) {
      float4 ra = *(const float4*)(A + (Rb+lrow)*512 + kc + lc4);
      float4 ca = *(const float4*)(A + (base+lrow)*512 + kc + lc4);
      LkR[lrow][lc4+0]=ra.x; LkR[lrow][lc4+1]=ra.y; LkR[lrow][lc4+2]=ra.z; LkR[lrow][lc4+3]=ra.w;
      LkC[lrow][lc4+0]=ca.x; LkC[lrow][lc4+1]=ca.y; LkC[lrow][lc4+2]=ca.z; LkC[lrow][lc4+3]=ca.w;
      __syncthreads();
      #pragma unroll
      for (int kk = 0; kk < 16; ++kk) {
        float a0=LkR[ty4+0][kk],a1=LkR[ty4+1][kk],a2=LkR[ty4+2][kk],a3=LkR[ty4+3][kk];
        float b0=LkC[tx4+0][kk],b1=LkC[tx4+1][kk],b2=LkC[tx4+2][kk],b3=LkC[tx4+3][kk];
        FMA16(acc,a0,a1,a2,a3,b0,b1,b2,b3)
      }
      __syncthreads();
    }
    #pragma unroll
    for (int u = 0; u < 4; ++u)
      #pragma unroll
      for (int v = 0; v < 4; ++v)
        Ds[ty4+u][tx4+v] = A[(Rb+ty4+u)*512 + base+tx4+v] - acc[u][v];
    for (int e = tid; e < 4096; e += 256) Vs[e>>6][e&63] = DINV[p*4096 + e];
    __syncthreads();
    // TRSM: Lsub = G * Dinv^T
    float acc2[4][4] = {{0.f}};
    for (int m = 0; m < 64; ++m) {
      float a0=Ds[ty4+0][m],a1=Ds[ty4+1][m],a2=Ds[ty4+2][m],a3=Ds[ty4+3][m];
      float b0=Vs[tx4+0][m],b1=Vs[tx4+1][m],b2=Vs[tx4+2][m],b3=Vs[tx4+3][m];
      FMA16(acc2,a0,a1,a2,a3,b0,b1,b2,b3)
    }
    #pragma unroll
    for (int u = 0; u < 4; ++u)
      #pragma unroll
      for (int v = 0; v < 4; ++v)
        A[(Rb+ty4+u)*512 + base+tx4+v] = acc2[u][v];
  }

  // ---- diag panel b: gram (K = 64b), then single-wave in-LDS factor+inverse
  {
    float acc[4][4] = {{0.f}};
    for (int kc = 0; kc < Rb; kc += 16) {
      float4 ca = *(const float4*)(A + (Rb+lrow)*512 + kc + lc4);
      LkC[lrow][lc4+0]=ca.x; LkC[lrow][lc4+1]=ca.y; LkC[lrow][lc4+2]=ca.z; LkC[lrow][lc4+3]=ca.w;
      __syncthreads();
      #pragma unroll
      for (int kk = 0; kk < 16; ++kk) {
        float a0=LkC[ty4+0][kk],a1=LkC[ty4+1][kk],a2=LkC[ty4+2][kk],a3=LkC[ty4+3][kk];
        float b0=LkC[tx4+0][kk],b1=LkC[tx4+1][kk],b2=LkC[tx4+2][kk],b3=LkC[tx4+3][kk];
        FMA16(acc,a0,a1,a2,a3,b0,b1,b2,b3)
      }
      __syncthreads();
    }
    #pragma unroll
    for (int u = 0; u < 4; ++u)
      #pragma unroll
      for (int v = 0; v < 4; ++v)
        Ds[ty4+u][tx4+v] = A[(Rb+ty4+u)*512 + Rb+tx4+v] - acc[u][v];
    __syncthreads();
    // single wave (tid<64), no barriers: same-wave LDS ordering via lgkmcnt.
    // Dynamic loops (NOT unrolled) to keep code size / compile time small.
    if (tid < 64) {
      int i = tid;
      // right-looking Cholesky; lane i owns row i
      for (int j = 0; j < 64; ++j) {
        float d = Ds[j][j];                 // broadcast read
        float r = rsqrtf(d);
        r = r*(1.5f - 0.5f*d*r*r);          // Newton refine
        if (i == j) rD[j] = r;
        float lij = 0.f;
        if (i >= j) {
          lij = Ds[i][j] * r;               // i==j: sqrt(d)
          Ds[i][j] = lij;
        }
        for (int k = j+1; k <= i; ++k)      // trailing update, own row
          Ds[i][k] -= lij * Ds[k][j];       // Ds[k][j] same-k broadcast per step
      }
      // V = L^-1; lane c = i owns column; V zero-filled so k<c terms vanish
      for (int ii = 0; ii < 64; ++ii) Vs[ii][i] = 0.0f;
      for (int ii = 0; ii < 64; ++ii) {
        float s = (ii == i) ? 1.0f : 0.0f;
        for (int k = 0; k < ii; ++k)
          s -= Ds[ii][k] * Vs[k][i];        // Ds broadcast; Vs own column
        Vs[ii][i] = s * rD[ii];
      }
      float* db = DINV + b*4096 + i;
      for (int ii = 0; ii < 64; ++ii) db[ii*64] = Vs[ii][i];  // coalesced
    }
    raise_flag(&flg[b], tid);
  }
}

// ------------- Linv tiles (stored transposed as LT), per-tile flags
__global__ __launch_bounds__(256) void k_linv(float* __restrict__ ws) {
  float* A = ws + OFF_A;
  float* LT = ws + OFF_LINV;
  float* DINV = ws + OFF_DINV;
  unsigned* flg = (unsigned*)(ws + OFF_FLAGS) + 8;
  int tid = threadIdx.x;
  int s = blockIdx.x >> 3, J = blockIdx.x & 7;
  if (s < J) {  // upper of Linv is zero -> LT rows 64J.., cols 64s..
    for (int e = tid; e < 4096; e += 256)
      LT[(64*J + (e>>6))*512 + 64*s + (e&63)] = 0.0f;
    return;
  }
  if (s == J) { // Linv[s][s] = Dinv_s ; store transposed
    for (int e = tid; e < 4096; e += 256) {
      int i = e >> 6, j = e & 63;
      LT[(64*s+j)*512 + 64*s + i] = DINV[s*4096 + e];
    }
    raise_flag(&flg[s*8+J], tid);
    return;
  }
  __shared__ float Ls[64][65];
  __shared__ float Vs[64][65];
  __shared__ float T[64][65];
  __shared__ float Dv[64][65];
  int ty4 = (tid >> 4)*4, tx4 = (tid & 15)*4;
  float acc[4][4] = {{0.f}};
  for (int k = J; k < s; ++k) {
    wait_flag(&flg[k*8+J], tid);
    for (int e = tid; e < 1024; e += 256) {
      int row = e >> 4, m4 = (e & 15)*4;
      float4 a = *(const float4*)(A + (64*s+row)*512 + 64*k + m4);
      Ls[row][m4+0]=a.x; Ls[row][m4+1]=a.y; Ls[row][m4+2]=a.z; Ls[row][m4+3]=a.w;
      float4 v = *(const float4*)(LT + (64*J+row)*512 + 64*k + m4);
      Vs[m4+0][row]=v.x; Vs[m4+1][row]=v.y; Vs[m4+2][row]=v.z; Vs[m4+3][row]=v.w;
    }
    __syncthreads();
    for (int m = 0; m < 64; ++m) {
      float a0=Ls[ty4+0][m],a1=Ls[ty4+1][m],a2=Ls[ty4+2][m],a3=Ls[ty4+3][m];
      float b0=Vs[m][tx4+0],b1=Vs[m][tx4+1],b2=Vs[m][tx4+2],b3=Vs[m][tx4+3];
      FMA16(acc,a0,a1,a2,a3,b0,b1,b2,b3)
    }
    __syncthreads();
  }
  #pragma unroll
  for (int u = 0; u < 4; ++u)
    #pragma unroll
    for (int v = 0; v < 4; ++v)
      T[ty4+u][tx4+v] = acc[u][v];
  for (int e = tid; e < 4096; e += 256) Dv[e>>6][e&63] = DINV[s*4096 + e];
  __syncthreads();
  float acc2[4][4] = {{0.f}};
  for (int m = 0; m < 64; ++m) {
    float a0=Dv[ty4+0][m],a1=Dv[ty4+1][m],a2=Dv[ty4+2][m],a3=Dv[ty4+3][m];
    float b0=T[m][tx4+0],b1=T[m][tx4+1],b2=T[m][tx4+2],b3=T[m][tx4+3];
    FMA16(acc2,a0,a1,a2,a3,b0,b1,b2,b3)
  }
  #pragma unroll
  for (int u = 0; u < 4; ++u)
    #pragma unroll
    for (int v = 0; v < 4; ++v)
      LT[(64*J+tx4+v)*512 + 64*s+ty4+u] = -acc2[u][v];
  raise_flag(&flg[s*8+J], tid);
}

// --------------------- w = Linv^T q_mu  (w[c] = sum_r LT[c][r] qmu[r])
__global__ __launch_bounds__(256) void k_wvec(const float* __restrict__ qmu,
                                              float* __restrict__ ws) {
  const float* LT = ws + OFF_LINV;
  float* W = ws + OFF_W;
  __shared__ float part[256];
  int tid = threadIdx.x;
  int c = blockIdx.x*64 + (tid >> 2);
  int q = tid & 3;
  float acc = 0.f;
  for (int r = q*128; r < q*128 + 128; r += 4) {
    float4 v = *(const float4*)(LT + c*512 + r);
    float4 m = *(const float4*)(qmu + r);
    acc += v.x*m.x + v.y*m.y + v.z*m.z + v.w*m.w;
  }
  part[tid] = acc;
  __syncthreads();
  if (q == 0) W[c] = part[tid]+part[tid+1]+part[tid+2]+part[tid+3];
}

// --------------------- main: per-point quadratic forms + ell partials
__global__ __launch_bounds__(256) void k_main(const float* __restrict__ X,
    const float* __restrict__ Yv, const float* __restrict__ Z,
    const float* __restrict__ llvP, const float* __restrict__ lsP,
    const float* __restrict__ osP, float* __restrict__ ws) {
  const float* LT = ws + OFF_LINV;
  const float* QC = ws + OFF_QC;
  const float* W = ws + OFF_W;
  float* PART = ws + OFF_PART;
  __shared__ float KL[8192];      // [c][pt] 512 x 16 : k tile, then l tile
  __shared__ float RD[2176];      // 2 x 64x17 reduction scratch
  __shared__ float wsh[512];
  __shared__ float Xs[16][8];
  __shared__ float pmv[16], lsqv[16], elli[16];
  int tid = threadIdx.x, B = blockIdx.x;
  float ls = lsP[0], os = osP[0], llv = llvP[0];
  float ils2 = 1.0f/(ls*ls);
  if (tid < 128) { int pp = tid>>3, d = tid&7; Xs[pp][d] = X[(B*16+pp)*8 + d]; }
  wsh[tid] = W[tid]; wsh[tid+256] = W[tid+256];
  __syncthreads();
  for (int e = tid; e < 8192; e += 256) {
    int cc = e >> 4, pp = e & 15;
    float4 z0 = *(const float4*)(Z + cc*8);
    float4 z1 = *(const float4*)(Z + cc*8 + 4);
    float d0=z0.x-Xs[pp][0], d1=z0.y-Xs[pp][1], d2=z0.z-Xs[pp][2], d3=z0.w-Xs[pp][3];
    float d4=z1.x-Xs[pp][4], d5=z1.y-Xs[pp][5], d6=z1.z-Xs[pp][6], d7=z1.w-Xs[pp][7];
    float sq = d0*d0+d1*d1+d2*d2+d3*d3+d4*d4+d5*d5+d6*d6+d7*d7;
    KL[e] = os*__expf(-0.5f*ils2*sq);
  }
  __syncthreads();
  int rq = tid >> 2;
  int rq4 = rq*4, pq4 = (tid & 3)*4;
  // phase A: l[r][pt] = sum_c LT[c][r] * k[c][pt]
  float acc0[4][4] = {{0.f}}, acc1[4][4] = {{0.f}};
  #pragma unroll 4
  for (int c = 0; c < 256; ++c) {
    float4 kv = *(const float4*)&KL[c*16 + pq4];
    float4 l0 = *(const float4*)(LT + c*512 + rq4);
    float4 l1 = *(const float4*)(LT + c*512 + 256 + rq4);
    FMA16(acc0, l0.x,l0.y,l0.z,l0.w, kv.x,kv.y,kv.z,kv.w)
    FMA16(acc1, l1.x,l1.y,l1.z,l1.w, kv.x,kv.y,kv.z,kv.w)
  }
  #pragma unroll 4
  for (int c = 256; c < 512; ++c) {
    float4 kv = *(const float4*)&KL[c*16 + pq4];
    float4 l1 = *(const float4*)(LT + c*512 + 256 + rq4);
    FMA16(acc1, l1.x,l1.y,l1.z,l1.w, kv.x,kv.y,kv.z,kv.w)
  }
  // pred-mean partials (KL still holds k) and ||l||^2 partials
  float pmp[4] = {0.f,0.f,0.f,0.f};
  for (int c8 = 0; c8 < 8; ++c8) {
    int cc2 = rq*8 + c8;
    float wv = wsh[cc2];
    pmp[0] += KL[cc2*16+pq4+0]*wv; pmp[1] += KL[cc2*16+pq4+1]*wv;
    pmp[2] += KL[cc2*16+pq4+2]*wv; pmp[3] += KL[cc2*16+pq4+3]*wv;
  }
  float lsp[4] = {0.f,0.f,0.f,0.f};
  #pragma unroll
  for (int u = 0; u < 4; ++u)
    #pragma unroll
    for (int v = 0; v < 4; ++v)
      lsp[v] += acc0[u][v]*acc0[u][v] + acc1[u][v]*acc1[u][v];
  #pragma unroll
  for (int v = 0; v < 4; ++v) {
    RD[rq*17 + pq4+v] = pmp[v];
    RD[1088 + rq*17 + pq4+v] = lsp[v];
  }
  __syncthreads();
  if (tid < 16) {
    float a = 0.f, b = 0.f;
    for (int r2 = 0; r2 < 64; ++r2) { a += RD[r2*17+tid]; b += RD[1088+r2*17+tid]; }
    pmv[tid] = a; lsqv[tid] = b;
  }
  __syncthreads();
  // overwrite KL with l
  #pragma unroll
  for (int u = 0; u < 4; ++u) {
    *(float4*)&KL[(rq4+u)*16 + pq4] = make_float4(acc0[u][0],acc0[u][1],acc0[u][2],acc0[u][3]);
    *(float4*)&KL[(256+rq4+u)*16 + pq4] = make_float4(acc1[u][0],acc1[u][1],acc1[u][2],acc1[u][3]);
  }
  __syncthreads();
  // phase B: u = QC @ l (QC symmetric -> row access), accumulate ||u||^2
  float ua0[4][4] = {{0.f}}, ua1[4][4] = {{0.f}};
  #pragma unroll 4
  for (int c = 0; c < 512; ++c) {
    float4 kv = *(const float4*)&KL[c*16 + pq4];
    float4 q0 = *(const float4*)(QC + c*512 + rq4);
    float4 q1 = *(const float4*)(QC + c*512 + 256 + rq4);
    FMA16(ua0, q0.x,q0.y,q0.z,q0.w, kv.x,kv.y,kv.z,kv.w)
    FMA16(ua1, q1.x,q1.y,q1.z,q1.w, kv.x,kv.y,kv.z,kv.w)
  }
  float usq[4] = {0.f,0.f,0.f,0.f};
  #pragma unroll
  for (int u = 0; u < 4; ++u)
    #pragma unroll
    for (int v = 0; v < 4; ++v)
      usq[v] += ua0[u][v]*ua0[u][v] + ua1[u][v]*ua1[u][v];
  #pragma unroll
  for (int v = 0; v < 4; ++v) RD[rq*17 + pq4+v] = usq[v];
  __syncthreads();
  if (tid < 16) {
    float us = 0.f;
    for (int r2 = 0; r2 < 64; ++r2) us += RD[r2*17+tid];
    int gi = B*16 + tid;
    float diff = Yv[gi] - pmv[tid];
    float diagc = os + us - lsqv[tid];
    float iss = __expf(-llv);
    elli[tid] = -0.5f*((diff*diff + diagc)*iss + (LOG2PI + llv));
  }
  __syncthreads();
  if (tid == 0) {
    float s = 0.f;
    #pragma unroll
    for (int i2 = 0; i2 < 16; ++i2) s += elli[i2];
    PART[B] = s;
  }
}

// --------------------- final scalar
__global__ __launch_bounds__(256) void k_final(const float* __restrict__ qmu,
    const float* __restrict__ qlv, float* __restrict__ ws, float* __restrict__ out) {
  __shared__ double sh[256];
  int tid = threadIdx.x;
  const float* QC = ws + OFF_QC;
  const float* PART = ws + OFF_PART;
  double pa = 0.0, tr = 0.0, mm = 0.0, ld = 0.0;
  for (int i = tid; i < 512; i += 256) {
    pa += (double)PART[i];
    tr += (double)QC[i*513];
    double q = (double)qmu[i]; mm += q*q;
    ld += (double)qlv[i*513];
  }
  double vals[4] = {pa, tr, mm, ld};
  double res[4];
  for (int t2 = 0; t2 < 4; ++t2) {
    sh[tid] = vals[t2]; __syncthreads();
    for (int s2 = 128; s2 > 0; s2 >>= 1) {
      if (tid < s2) sh[tid] += sh[tid+s2];
      __syncthreads();
    }
    res[t2] = sh[0]; __syncthreads();
  }
  if (tid == 0) {
    double n = 8192.0;
    double ell = res[0]/n;
    double kl = 0.5*(res[1] + res[2] - 512.0 - res[3])/n;
    out[0] = (float)(ell - kl);
  }
}

extern "C" void kernel_launch(void* const* d_in, const int* in_sizes, int n_in,
                              void* d_out, int out_size, void* d_ws, size_t ws_size,
                              hipStream_t stream) {
  (void)in_sizes; (void)n_in; (void)out_size; (void)ws_size;
  const float* X   = (const float*)d_in[0];
  const float* Y   = (const float*)d_in[1];
  const float* Z   = (const float*)d_in[2];
  const float* qmu = (const float*)d_in[3];
  const float* qlv = (const float*)d_in[4];
  const float* llv = (const float*)d_in[5];
  const float* ls  = (const float*)d_in[6];
  const float* os  = (const float*)d_in[7];
  float* ws = (float*)d_ws;
  float* out = (float*)d_out;

  k_prep<<<2048, 256, 0, stream>>>(Z, qlv, ls, os, ws);
  k_gemm_nt<<<dim3(8,8), 256, 0, stream>>>(ws+OFF_QS, ws+OFF_QS, ws+OFF_QC, JIT);
  k_chol_all<<<8, 256, 0, stream>>>(ws);
  k_linv<<<64, 256, 0, stream>>>(ws);
  k_wvec<<<8, 256, 0, stream>>>(qmu, ws);
  k_main<<<512, 256, 0, stream>>>(X, Y, Z, llv, ls, os, ws);
  k_final<<<1, 256, 0, stream>>>(qmu, qlv, ws, out);
}

// Round 6
// 761.820 us; speedup vs baseline: 1.7334x; 1.7334x over previous
//
#include <hip/hip_runtime.h>
#include <math.h>

#define MI 512
#define NPT 8192
#define JIT 1e-6f
#define LOG2PI 1.8378770664093453f

// ws float offsets
#define OFF_A     0         // 512x512 Kuu -> L (lower; diag blocks never read downstream)
#define OFF_LINV  262144    // 512x512 Linv^T (LT[r][c] = Linv[c][r])
#define OFF_QS    524288    // 512x512 q_sqrt
#define OFF_QC    786432    // 512x512 q_cov (symmetric)
#define OFF_DINV  1048576   // 8 x 64x64 diag-block inverses
#define OFF_W     1081344   // 512  w = Linv^T q_mu
#define OFF_PART  1081856   // 512 block partial ell sums
#define OFF_FLAGS 1082368   // [0..7] chol panel done, [8..71] linv tiles

#define FMA16(ACC,a0,a1,a2,a3,b0,b1,b2,b3) \
  ACC[0][0]+=a0*b0; ACC[0][1]+=a0*b1; ACC[0][2]+=a0*b2; ACC[0][3]+=a0*b3; \
  ACC[1][0]+=a1*b0; ACC[1][1]+=a1*b1; ACC[1][2]+=a1*b2; ACC[1][3]+=a1*b3; \
  ACC[2][0]+=a2*b0; ACC[2][1]+=a2*b1; ACC[2][2]+=a2*b2; ACC[2][3]+=a2*b3; \
  ACC[3][0]+=a3*b0; ACC[3][1]+=a3*b1; ACC[3][2]+=a3*b2; ACC[3][3]+=a3*b3;

__device__ __forceinline__ void wait_flag(unsigned* f, int tid) {
  if (tid == 0) {
    while (__hip_atomic_load(f, __ATOMIC_RELAXED, __HIP_MEMORY_SCOPE_AGENT) == 0)
      __builtin_amdgcn_s_sleep(2);
    __builtin_amdgcn_fence(__ATOMIC_ACQUIRE, "agent");
  }
  __syncthreads();
}
__device__ __forceinline__ void raise_flag(unsigned* f, int tid) {
  __syncthreads();
  if (tid == 0) {
    __builtin_amdgcn_fence(__ATOMIC_RELEASE, "agent");
    __hip_atomic_store(f, 1u, __ATOMIC_RELAXED, __HIP_MEMORY_SCOPE_AGENT);
  }
}

// ---------------------------------------------------------------- prep
__global__ __launch_bounds__(256) void k_prep(const float* __restrict__ Z,
    const float* __restrict__ qlv, const float* __restrict__ lsP,
    const float* __restrict__ osP, float* __restrict__ ws) {
  int u = blockIdx.x*256 + threadIdx.x;
  if (blockIdx.x == 0 && threadIdx.x < 128)
    ((unsigned*)(ws + OFF_FLAGS))[threadIdx.x] = 0u;
  float ls = lsP[0], os = osP[0];
  float ils2 = 1.0f/(ls*ls);
  if (u < MI*MI) {
    int i = u >> 9, j = u & 511;
    float4 a0 = *(const float4*)(Z + i*8);
    float4 a1 = *(const float4*)(Z + i*8 + 4);
    float4 b0 = *(const float4*)(Z + j*8);
    float4 b1 = *(const float4*)(Z + j*8 + 4);
    float d0=a0.x-b0.x, d1=a0.y-b0.y, d2=a0.z-b0.z, d3=a0.w-b0.w;
    float d4=a1.x-b1.x, d5=a1.y-b1.y, d6=a1.z-b1.z, d7=a1.w-b1.w;
    float sq = d0*d0+d1*d1+d2*d2+d3*d3+d4*d4+d5*d5+d6*d6+d7*d7;
    float v = os*__expf(-0.5f*ils2*sq);
    if (i==j) v += JIT;
    ws[OFF_A + u] = v;
  } else {
    int w2 = u - MI*MI;
    if (w2 < MI*MI) {
      int i = w2 >> 9, j = w2 & 511;
      ws[OFF_QS + w2] = (j <= i) ? __expf(0.5f*qlv[w2]) : 0.0f;
    }
  }
}

// ------------------------------------------------- O = X Y^T + adiag*I (K=512)
__global__ __launch_bounds__(256) void k_gemm_nt(const float* __restrict__ X,
    const float* __restrict__ Y, float* __restrict__ O, float adiag) {
  __shared__ float Xs[64][20], Ys[64][20];
  int tid = threadIdx.x;
  int bi = blockIdx.y, bj = blockIdx.x;
  int ty4 = (tid >> 4)*4, tx4 = (tid & 15)*4;
  int lrow = tid >> 2, lc4 = (tid & 3)*4;
  float acc[4][4] = {{0.f}};
  for (int kc = 0; kc < 512; kc += 16) {
    float4 xa = *(const float4*)(X + (bi*64+lrow)*512 + kc + lc4);
    float4 ya = *(const float4*)(Y + (bj*64+lrow)*512 + kc + lc4);
    Xs[lrow][lc4+0]=xa.x; Xs[lrow][lc4+1]=xa.y; Xs[lrow][lc4+2]=xa.z; Xs[lrow][lc4+3]=xa.w;
    Ys[lrow][lc4+0]=ya.x; Ys[lrow][lc4+1]=ya.y; Ys[lrow][lc4+2]=ya.z; Ys[lrow][lc4+3]=ya.w;
    __syncthreads();
    #pragma unroll
    for (int kk = 0; kk < 16; ++kk) {
      float a0=Xs[ty4+0][kk],a1=Xs[ty4+1][kk],a2=Xs[ty4+2][kk],a3=Xs[ty4+3][kk];
      float b0=Ys[tx4+0][kk],b1=Ys[tx4+1][kk],b2=Ys[tx4+2][kk],b3=Ys[tx4+3][kk];
      FMA16(acc,a0,a1,a2,a3,b0,b1,b2,b3)
    }
    __syncthreads();
  }
  #pragma unroll
  for (int u = 0; u < 4; ++u)
    #pragma unroll
    for (int v = 0; v < 4; ++v) {
      int gi = bi*64+ty4+u, gj = bj*64+tx4+v;
      float o = acc[u][v]; if (gi==gj) o += adiag;
      O[gi*512+gj] = o;
    }
}

// ------------- fused Cholesky: block b owns row-block b; flag[p] = panel p done
__global__ __launch_bounds__(256) void k_chol_all(float* __restrict__ ws) {
  float* A = ws + OFF_A;
  float* DINV = ws + OFF_DINV;
  unsigned* flg = (unsigned*)(ws + OFF_FLAGS);
  __shared__ float LkR[64][20], LkC[64][20];
  __shared__ float Ds[64][65];
  __shared__ float Vs[64][65];
  int tid = threadIdx.x, b = blockIdx.x;
  int ty4 = (tid >> 4)*4, tx4 = (tid & 15)*4;
  int lrow = tid >> 2, lc4 = (tid & 3)*4;
  int Rb = b*64;

  // ---- sub-panel columns p = 0..b-1 (left-looking)
  for (int p = 0; p < b; ++p) {
    int base = p*64;
    wait_flag(&flg[p], tid);
    float acc[4][4] = {{0.f}};
    for (int kc = 0; kc < base; kc += 16) {
      float4 ra = *(const float4*)(A + (Rb+lrow)*512 + kc + lc4);
      float4 ca = *(const float4*)(A + (base+lrow)*512 + kc + lc4);
      LkR[lrow][lc4+0]=ra.x; LkR[lrow][lc4+1]=ra.y; LkR[lrow][lc4+2]=ra.z; LkR[lrow][lc4+3]=ra.w;
      LkC[lrow][lc4+0]=ca.x; LkC[lrow][lc4+1]=ca.y; LkC[lrow][lc4+2]=ca.z; LkC[lrow][lc4+3]=ca.w;
      __syncthreads();
      #pragma unroll
      for (int kk = 0; kk < 16; ++kk) {
        float a0=LkR[ty4+0][kk],a1=LkR[ty4+1][kk],a2=LkR[ty4+2][kk],a3=LkR[ty4+3][kk];
        float b0=LkC[tx4+0][kk],b1=LkC[tx4+1][kk],b2=LkC[tx4+2][kk],b3=LkC[tx4+3][kk];
        FMA16(acc,a0,a1,a2,a3,b0,b1,b2,b3)
      }
      __syncthreads();
    }
    #pragma unroll
    for (int u = 0; u < 4; ++u)
      #pragma unroll
      for (int v = 0; v < 4; ++v)
        Ds[ty4+u][tx4+v] = A[(Rb+ty4+u)*512 + base+tx4+v] - acc[u][v];
    for (int e = tid; e < 4096; e += 256) Vs[e>>6][e&63] = DINV[p*4096 + e];
    __syncthreads();
    // TRSM: Lsub = G * Dinv^T
    float acc2[4][4] = {{0.f}};
    for (int m = 0; m < 64; ++m) {
      float a0=Ds[ty4+0][m],a1=Ds[ty4+1][m],a2=Ds[ty4+2][m],a3=Ds[ty4+3][m];
      float b0=Vs[tx4+0][m],b1=Vs[tx4+1][m],b2=Vs[tx4+2][m],b3=Vs[tx4+3][m];
      FMA16(acc2,a0,a1,a2,a3,b0,b1,b2,b3)
    }
    #pragma unroll
    for (int u = 0; u < 4; ++u)
      #pragma unroll
      for (int v = 0; v < 4; ++v)
        A[(Rb+ty4+u)*512 + base+tx4+v] = acc2[u][v];
    __syncthreads();
  }

  // ---- diag panel b: gram (K = 64b) into Ds; zero Vs
  {
    float acc[4][4] = {{0.f}};
    for (int kc = 0; kc < Rb; kc += 16) {
      float4 ca = *(const float4*)(A + (Rb+lrow)*512 + kc + lc4);
      LkC[lrow][lc4+0]=ca.x; LkC[lrow][lc4+1]=ca.y; LkC[lrow][lc4+2]=ca.z; LkC[lrow][lc4+3]=ca.w;
      __syncthreads();
      #pragma unroll
      for (int kk = 0; kk < 16; ++kk) {
        float a0=LkC[ty4+0][kk],a1=LkC[ty4+1][kk],a2=LkC[ty4+2][kk],a3=LkC[ty4+3][kk];
        float b0=LkC[tx4+0][kk],b1=LkC[tx4+1][kk],b2=LkC[tx4+2][kk],b3=LkC[tx4+3][kk];
        FMA16(acc,a0,a1,a2,a3,b0,b1,b2,b3)
      }
      __syncthreads();
    }
    #pragma unroll
    for (int u = 0; u < 4; ++u)
      #pragma unroll
      for (int v = 0; v < 4; ++v)
        Ds[ty4+u][tx4+v] = A[(Rb+ty4+u)*512 + Rb+tx4+v] - acc[u][v];
    for (int e = tid; e < 4096; e += 256) Vs[e>>6][e&63] = 0.0f;
    __syncthreads();
  }

  // ---- factor 64x64 via 16-wide sub-panels (serial math in registers)
  for (int t = 0; t < 4; ++t) {
    const int c0 = t*16;
    // (a) one wave: factor 16x16 + triangular inverse; L -> Ds, V16 -> Vs diag
    if (tid < 16) {
      float a[16];
      #pragma unroll
      for (int j = 0; j < 16; ++j) a[j] = Ds[c0+tid][c0+j];
      float rr = 0.f;                                // lane j keeps 1/L[j][j]
      #pragma unroll
      for (int j = 0; j < 16; ++j) {
        float d = __shfl(a[j], j);
        float r = rsqrtf(d);
        r = r*(1.5f - 0.5f*d*r*r);                   // Newton refine
        if (tid == j) rr = r;
        a[j] *= r;
        #pragma unroll
        for (int k = j+1; k < 16; ++k)
          a[k] -= a[j]*__shfl(a[j], k);
      }
      #pragma unroll
      for (int j = 0; j < 16; ++j)
        Ds[c0+tid][c0+j] = (j <= tid) ? a[j] : 0.0f;
      float v[16];                                   // lane tid owns column tid
      #pragma unroll
      for (int i = 0; i < 16; ++i) {
        float s = (tid == i) ? 1.0f : 0.0f;
        #pragma unroll
        for (int k = 0; k < i; ++k)
          s -= Ds[c0+i][c0+k]*v[k];                  // broadcast reads, pipelined
        v[i] = s * __shfl(rr, i);
      }
      #pragma unroll
      for (int i = 0; i < 16; ++i)
        Vs[c0+i][c0+tid] = v[i];
    }
    __syncthreads();
    if (t < 3) {
      const int cnt = 48 - c0;
      const int r0 = c0 + 16;
      // (b) TRSM rows below: Lsub[r][j] = sum_m A21[r][m]*V16[j][m]
      float res[3];
      int nout = cnt*16, idx = 0;
      for (int e = tid; e < nout; e += 256, ++idx) {
        int r = r0 + (e >> 4), j = e & 15;
        float s = 0.f;
        #pragma unroll
        for (int m = 0; m < 16; ++m)
          s += Ds[r][c0+m]*Vs[c0+j][c0+m];
        res[idx] = s;
      }
      __syncthreads();
      idx = 0;
      for (int e = tid; e < nout; e += 256, ++idx)
        Ds[r0 + (e >> 4)][c0 + (e & 15)] = res[idx];
      __syncthreads();
      // (c) trailing update: A22[r][c] -= sum_m Lsub[r][m]*Lsub[c][m]
      for (int e = tid; e < cnt*cnt; e += 256) {
        int r = r0 + e/cnt, c = r0 + e%cnt;
        float s = 0.f;
        #pragma unroll
        for (int m = 0; m < 16; ++m)
          s += Ds[r][c0+m]*Ds[c][c0+m];
        Ds[r][c] -= s;
      }
      __syncthreads();
    }
  }

  // ---- assemble off-diag Dinv: V[J][I] = -V_JJ * (sum_{k=I..J-1} L[J][k] V[k][I])
  {
    float* TMP = &LkR[0][0];                          // 1280 floats >= 3*272
    for (int d = 1; d < 4; ++d) {
      int nout = (4-d)*256;
      for (int e = tid; e < nout; e += 256) {
        int bs = e >> 8, I = bs, J = I + d;
        int i = (e >> 4) & 15, c = e & 15;
        float s = 0.f;
        for (int k = I; k < J; ++k) {
          #pragma unroll
          for (int m = 0; m < 16; ++m)
            s += Ds[J*16+i][k*16+m]*Vs[k*16+m][I*16+c];
        }
        TMP[bs*272 + i*17 + c] = s;
      }
      __syncthreads();
      for (int e = tid; e < nout; e += 256) {
        int bs = e >> 8, I = bs, J = I + d;
        int i = (e >> 4) & 15, c = e & 15;
        float s = 0.f;
        #pragma unroll
        for (int m = 0; m < 16; ++m)
          s += Vs[J*16+i][J*16+m]*TMP[bs*272 + m*17 + c];
        Vs[J*16+i][I*16+c] = -s;
      }
      __syncthreads();
    }
  }
  for (int e = tid; e < 4096; e += 256)
    DINV[b*4096 + e] = Vs[e>>6][e&63];
  raise_flag(&flg[b], tid);
}

// ------------- Linv tiles (stored transposed as LT), per-tile flags
__global__ __launch_bounds__(256) void k_linv(float* __restrict__ ws) {
  float* A = ws + OFF_A;
  float* LT = ws + OFF_LINV;
  float* DINV = ws + OFF_DINV;
  unsigned* flg = (unsigned*)(ws + OFF_FLAGS) + 8;
  int tid = threadIdx.x;
  int s = blockIdx.x >> 3, J = blockIdx.x & 7;
  if (s < J) {  // upper of Linv is zero -> LT rows 64J.., cols 64s..
    for (int e = tid; e < 4096; e += 256)
      LT[(64*J + (e>>6))*512 + 64*s + (e&63)] = 0.0f;
    return;
  }
  if (s == J) { // Linv[s][s] = Dinv_s ; store transposed
    for (int e = tid; e < 4096; e += 256) {
      int i = e >> 6, j = e & 63;
      LT[(64*s+j)*512 + 64*s + i] = DINV[s*4096 + e];
    }
    raise_flag(&flg[s*8+J], tid);
    return;
  }
  __shared__ float Ls[64][65];
  __shared__ float Vs[64][65];
  __shared__ float T[64][65];
  __shared__ float Dv[64][65];
  int ty4 = (tid >> 4)*4, tx4 = (tid & 15)*4;
  float acc[4][4] = {{0.f}};
  for (int k = J; k < s; ++k) {
    wait_flag(&flg[k*8+J], tid);
    for (int e = tid; e < 1024; e += 256) {
      int row = e >> 4, m4 = (e & 15)*4;
      float4 a = *(const float4*)(A + (64*s+row)*512 + 64*k + m4);
      Ls[row][m4+0]=a.x; Ls[row][m4+1]=a.y; Ls[row][m4+2]=a.z; Ls[row][m4+3]=a.w;
      float4 v = *(const float4*)(LT + (64*J+row)*512 + 64*k + m4);
      Vs[m4+0][row]=v.x; Vs[m4+1][row]=v.y; Vs[m4+2][row]=v.z; Vs[m4+3][row]=v.w;
    }
    __syncthreads();
    for (int m = 0; m < 64; ++m) {
      float a0=Ls[ty4+0][m],a1=Ls[ty4+1][m],a2=Ls[ty4+2][m],a3=Ls[ty4+3][m];
      float b0=Vs[m][tx4+0],b1=Vs[m][tx4+1],b2=Vs[m][tx4+2],b3=Vs[m][tx4+3];
      FMA16(acc,a0,a1,a2,a3,b0,b1,b2,b3)
    }
    __syncthreads();
  }
  #pragma unroll
  for (int u = 0; u < 4; ++u)
    #pragma unroll
    for (int v = 0; v < 4; ++v)
      T[ty4+u][tx4+v] = acc[u][v];
  for (int e = tid; e < 4096; e += 256) Dv[e>>6][e&63] = DINV[s*4096 + e];
  __syncthreads();
  float acc2[4][4] = {{0.f}};
  for (int m = 0; m < 64; ++m) {
    float a0=Dv[ty4+0][m],a1=Dv[ty4+1][m],a2=Dv[ty4+2][m],a3=Dv[ty4+3][m];
    float b0=T[m][tx4+0],b1=T[m][tx4+1],b2=T[m][tx4+2],b3=T[m][tx4+3];
    FMA16(acc2,a0,a1,a2,a3,b0,b1,b2,b3)
  }
  #pragma unroll
  for (int u = 0; u < 4; ++u)
    #pragma unroll
    for (int v = 0; v < 4; ++v)
      LT[(64*J+tx4+v)*512 + 64*s+ty4+u] = -acc2[u][v];
  raise_flag(&flg[s*8+J], tid);
}

// --------------------- w = Linv^T q_mu  (w[c] = sum_r LT[c][r] qmu[r])
__global__ __launch_bounds__(256) void k_wvec(const float* __restrict__ qmu,
                                              float* __restrict__ ws) {
  const float* LT = ws + OFF_LINV;
  float* W = ws + OFF_W;
  __shared__ float part[256];
  int tid = threadIdx.x;
  int c = blockIdx.x*64 + (tid >> 2);
  int q = tid & 3;
  float acc = 0.f;
  for (int r = q*128; r < q*128 + 128; r += 4) {
    float4 v = *(const float4*)(LT + c*512 + r);
    float4 m = *(const float4*)(qmu + r);
    acc += v.x*m.x + v.y*m.y + v.z*m.z + v.w*m.w;
  }
  part[tid] = acc;
  __syncthreads();
  if (q == 0) W[c] = part[tid]+part[tid+1]+part[tid+2]+part[tid+3];
}

// --------------------- main: per-point quadratic forms + ell partials
__global__ __launch_bounds__(256) void k_main(const float* __restrict__ X,
    const float* __restrict__ Yv, const float* __restrict__ Z,
    const float* __restrict__ llvP, const float* __restrict__ lsP,
    const float* __restrict__ osP, float* __restrict__ ws) {
  const float* LT = ws + OFF_LINV;
  const float* QC = ws + OFF_QC;
  const float* W = ws + OFF_W;
  float* PART = ws + OFF_PART;
  __shared__ float KL[8192];      // [c][pt] 512 x 16 : k tile, then l tile
  __shared__ float RD[2176];      // 2 x 64x17 reduction scratch
  __shared__ float wsh[512];
  __shared__ float Xs[16][8];
  __shared__ float pmv[16], lsqv[16], elli[16];
  int tid = threadIdx.x, B = blockIdx.x;
  float ls = lsP[0], os = osP[0], llv = llvP[0];
  float ils2 = 1.0f/(ls*ls);
  if (tid < 128) { int pp = tid>>3, d = tid&7; Xs[pp][d] = X[(B*16+pp)*8 + d]; }
  wsh[tid] = W[tid]; wsh[tid+256] = W[tid+256];
  __syncthreads();
  for (int e = tid; e < 8192; e += 256) {
    int cc = e >> 4, pp = e & 15;
    float4 z0 = *(const float4*)(Z + cc*8);
    float4 z1 = *(const float4*)(Z + cc*8 + 4);
    float d0=z0.x-Xs[pp][0], d1=z0.y-Xs[pp][1], d2=z0.z-Xs[pp][2], d3=z0.w-Xs[pp][3];
    float d4=z1.x-Xs[pp][4], d5=z1.y-Xs[pp][5], d6=z1.z-Xs[pp][6], d7=z1.w-Xs[pp][7];
    float sq = d0*d0+d1*d1+d2*d2+d3*d3+d4*d4+d5*d5+d6*d6+d7*d7;
    KL[e] = os*__expf(-0.5f*ils2*sq);
  }
  __syncthreads();
  int rq = tid >> 2;
  int rq4 = rq*4, pq4 = (tid & 3)*4;
  // phase A: l[r][pt] = sum_c LT[c][r] * k[c][pt]
  float acc0[4][4] = {{0.f}}, acc1[4][4] = {{0.f}};
  #pragma unroll 4
  for (int c = 0; c < 256; ++c) {
    float4 kv = *(const float4*)&KL[c*16 + pq4];
    float4 l0 = *(const float4*)(LT + c*512 + rq4);
    float4 l1 = *(const float4*)(LT + c*512 + 256 + rq4);
    FMA16(acc0, l0.x,l0.y,l0.z,l0.w, kv.x,kv.y,kv.z,kv.w)
    FMA16(acc1, l1.x,l1.y,l1.z,l1.w, kv.x,kv.y,kv.z,kv.w)
  }
  #pragma unroll 4
  for (int c = 256; c < 512; ++c) {
    float4 kv = *(const float4*)&KL[c*16 + pq4];
    float4 l1 = *(const float4*)(LT + c*512 + 256 + rq4);
    FMA16(acc1, l1.x,l1.y,l1.z,l1.w, kv.x,kv.y,kv.z,kv.w)
  }
  // pred-mean partials (KL still holds k) and ||l||^2 partials
  float pmp[4] = {0.f,0.f,0.f,0.f};
  for (int c8 = 0; c8 < 8; ++c8) {
    int cc2 = rq*8 + c8;
    float wv = wsh[cc2];
    pmp[0] += KL[cc2*16+pq4+0]*wv; pmp[1] += KL[cc2*16+pq4+1]*wv;
    pmp[2] += KL[cc2*16+pq4+2]*wv; pmp[3] += KL[cc2*16+pq4+3]*wv;
  }
  float lsp[4] = {0.f,0.f,0.f,0.f};
  #pragma unroll
  for (int u = 0; u < 4; ++u)
    #pragma unroll
    for (int v = 0; v < 4; ++v)
      lsp[v] += acc0[u][v]*acc0[u][v] + acc1[u][v]*acc1[u][v];
  #pragma unroll
  for (int v = 0; v < 4; ++v) {
    RD[rq*17 + pq4+v] = pmp[v];
    RD[1088 + rq*17 + pq4+v] = lsp[v];
  }
  __syncthreads();
  if (tid < 16) {
    float a = 0.f, b = 0.f;
    for (int r2 = 0; r2 < 64; ++r2) { a += RD[r2*17+tid]; b += RD[1088+r2*17+tid]; }
    pmv[tid] = a; lsqv[tid] = b;
  }
  __syncthreads();
  // overwrite KL with l
  #pragma unroll
  for (int u = 0; u < 4; ++u) {
    *(float4*)&KL[(rq4+u)*16 + pq4] = make_float4(acc0[u][0],acc0[u][1],acc0[u][2],acc0[u][3]);
    *(float4*)&KL[(256+rq4+u)*16 + pq4] = make_float4(acc1[u][0],acc1[u][1],acc1[u][2],acc1[u][3]);
  }
  __syncthreads();
  // phase B: u = QC @ l (QC symmetric -> row access), accumulate ||u||^2
  float ua0[4][4] = {{0.f}}, ua1[4][4] = {{0.f}};
  #pragma unroll 4
  for (int c = 0; c < 512; ++c) {
    float4 kv = *(const float4*)&KL[c*16 + pq4];
    float4 q0 = *(const float4*)(QC + c*512 + rq4);
    float4 q1 = *(const float4*)(QC + c*512 + 256 + rq4);
    FMA16(ua0, q0.x,q0.y,q0.z,q0.w, kv.x,kv.y,kv.z,kv.w)
    FMA16(ua1, q1.x,q1.y,q1.z,q1.w, kv.x,kv.y,kv.z,kv.w)
  }
  float usq[4] = {0.f,0.f,0.f,0.f};
  #pragma unroll
  for (int u = 0; u < 4; ++u)
    #pragma unroll
    for (int v = 0; v < 4; ++v)
      usq[v] += ua0[u][v]*ua0[u][v] + ua1[u][v]*ua1[u][v];
  #pragma unroll
  for (int v = 0; v < 4; ++v) RD[rq*17 + pq4+v] = usq[v];
  __syncthreads();
  if (tid < 16) {
    float us = 0.f;
    for (int r2 = 0; r2 < 64; ++r2) us += RD[r2*17+tid];
    int gi = B*16 + tid;
    float diff = Yv[gi] - pmv[tid];
    float diagc = os + us - lsqv[tid];
    float iss = __expf(-llv);
    elli[tid] = -0.5f*((diff*diff + diagc)*iss + (LOG2PI + llv));
  }
  __syncthreads();
  if (tid == 0) {
    float s = 0.f;
    #pragma unroll
    for (int i2 = 0; i2 < 16; ++i2) s += elli[i2];
    PART[B] = s;
  }
}

// --------------------- final scalar
__global__ __launch_bounds__(256) void k_final(const float* __restrict__ qmu,
    const float* __restrict__ qlv, float* __restrict__ ws, float* __restrict__ out) {
  __shared__ double sh[256];
  int tid = threadIdx.x;
  const float* QC = ws + OFF_QC;
  const float* PART = ws + OFF_PART;
  double pa = 0.0, tr = 0.0, mm = 0.0, ld = 0.0;
  for (int i = tid; i < 512; i += 256) {
    pa += (double)PART[i];
    tr += (double)QC[i*513];
    double q = (double)qmu[i]; mm += q*q;
    ld += (double)qlv[i*513];
  }
  double vals[4] = {pa, tr, mm, ld};
  double res[4];
  for (int t2 = 0; t2 < 4; ++t2) {
    sh[tid] = vals[t2]; __syncthreads();
    for (int s2 = 128; s2 > 0; s2 >>= 1) {
      if (tid < s2) sh[tid] += sh[tid+s2];
      __syncthreads();
    }
    res[t2] = sh[0]; __syncthreads();
  }
  if (tid == 0) {
    double n = 8192.0;
    double ell = res[0]/n;
    double kl = 0.5*(res[1] + res[2] - 512.0 - res[3])/n;
    out[0] = (float)(ell - kl);
  }
}

extern "C" void kernel_launch(void* const* d_in, const int* in_sizes, int n_in,
                              void* d_out, int out_size, void* d_ws, size_t ws_size,
                              hipStream_t stream) {
  (void)in_sizes; (void)n_in; (void)out_size; (void)ws_size;
  const float* X   = (const float*)d_in[0];
  const float* Y   = (const float*)d_in[1];
  const float* Z   = (const float*)d_in[2];
  const float* qmu = (const float*)d_in[3];
  const float* qlv = (const float*)d_in[4];
  const float* llv = (const float*)d_in[5];
  const float* ls  = (const float*)d_in[6];
  const float* os  = (const float*)d_in[7];
  float* ws = (float*)d_ws;
  float* out = (float*)d_out;

  k_prep<<<2048, 256, 0, stream>>>(Z, qlv, ls, os, ws);
  k_gemm_nt<<<dim3(8,8), 256, 0, stream>>>(ws+OFF_QS, ws+OFF_QS, ws+OFF_QC, JIT);
  k_chol_all<<<8, 256, 0, stream>>>(ws);
  k_linv<<<64, 256, 0, stream>>>(ws);
  k_wvec<<<8, 256, 0, stream>>>(qmu, ws);
  k_main<<<512, 256, 0, stream>>>(X, Y, Z, llv, ls, os, ws);
  k_final<<<1, 256, 0, stream>>>(qmu, qlv, ws, out);
}

// Round 7
// 561.013 us; speedup vs baseline: 2.3538x; 1.3579x over previous
//
#include <hip/hip_runtime.h>
#include <math.h>

#define MI 512
#define NPT 8192
#define JIT 1e-6f
#define LOG2PI 1.8378770664093453f

// ws float offsets
#define OFF_A     0         // 512x512 Kuu -> L (lower; diag blocks never read downstream)
#define OFF_LINV  262144    // 512x512 Linv^T (LT[r][c] = Linv[c][r])
#define OFF_QS    524288    // 512x512 q_sqrt
#define OFF_QC    786432    // 512x512 q_cov (symmetric)
#define OFF_DINV  1048576   // 8 x 64x64 diag-block inverses
#define OFF_W     1081344   // 512  w = Linv^T q_mu
#define OFF_PART  1081856   // 512 block partial ell sums
#define OFF_FLAGS 1082368   // [0..7] dinv ready, [8..71] lsub tile (b*8+p), [72..135] linv tiles

#define RS 517              // LDS row stride for the resident row-block (bank-friendly)

#define FMA16(ACC,a0,a1,a2,a3,b0,b1,b2,b3) \
  ACC[0][0]+=a0*b0; ACC[0][1]+=a0*b1; ACC[0][2]+=a0*b2; ACC[0][3]+=a0*b3; \
  ACC[1][0]+=a1*b0; ACC[1][1]+=a1*b1; ACC[1][2]+=a1*b2; ACC[1][3]+=a1*b3; \
  ACC[2][0]+=a2*b0; ACC[2][1]+=a2*b1; ACC[2][2]+=a2*b2; ACC[2][3]+=a2*b3; \
  ACC[3][0]+=a3*b0; ACC[3][1]+=a3*b1; ACC[3][2]+=a3*b2; ACC[3][3]+=a3*b3;

__device__ __forceinline__ void wait_flag(unsigned* f, int tid) {
  if (tid == 0) {
    while (__hip_atomic_load(f, __ATOMIC_RELAXED, __HIP_MEMORY_SCOPE_AGENT) == 0)
      __builtin_amdgcn_s_sleep(2);
    __builtin_amdgcn_fence(__ATOMIC_ACQUIRE, "agent");
  }
  __syncthreads();
}
__device__ __forceinline__ void raise_flag(unsigned* f, int tid) {
  __syncthreads();
  if (tid == 0) {
    __builtin_amdgcn_fence(__ATOMIC_RELEASE, "agent");
    __hip_atomic_store(f, 1u, __ATOMIC_RELAXED, __HIP_MEMORY_SCOPE_AGENT);
  }
}

// ---------------------------------------------------------------- prep
__global__ __launch_bounds__(256) void k_prep(const float* __restrict__ Z,
    const float* __restrict__ qlv, const float* __restrict__ lsP,
    const float* __restrict__ osP, float* __restrict__ ws) {
  int u = blockIdx.x*256 + threadIdx.x;
  if (blockIdx.x == 0 && threadIdx.x < 160)
    ((unsigned*)(ws + OFF_FLAGS))[threadIdx.x] = 0u;
  float ls = lsP[0], os = osP[0];
  float ils2 = 1.0f/(ls*ls);
  if (u < MI*MI) {
    int i = u >> 9, j = u & 511;
    float4 a0 = *(const float4*)(Z + i*8);
    float4 a1 = *(const float4*)(Z + i*8 + 4);
    float4 b0 = *(const float4*)(Z + j*8);
    float4 b1 = *(const float4*)(Z + j*8 + 4);
    float d0=a0.x-b0.x, d1=a0.y-b0.y, d2=a0.z-b0.z, d3=a0.w-b0.w;
    float d4=a1.x-b1.x, d5=a1.y-b1.y, d6=a1.z-b1.z, d7=a1.w-b1.w;
    float sq = d0*d0+d1*d1+d2*d2+d3*d3+d4*d4+d5*d5+d6*d6+d7*d7;
    float v = os*__expf(-0.5f*ils2*sq);
    if (i==j) v += JIT;
    ws[OFF_A + u] = v;
  } else {
    int w2 = u - MI*MI;
    if (w2 < MI*MI) {
      int i = w2 >> 9, j = w2 & 511;
      ws[OFF_QS + w2] = (j <= i) ? __expf(0.5f*qlv[w2]) : 0.0f;
    }
  }
}

// ------------------------------------------------- O = X Y^T + adiag*I (K=512)
__global__ __launch_bounds__(256) void k_gemm_nt(const float* __restrict__ X,
    const float* __restrict__ Y, float* __restrict__ O, float adiag) {
  __shared__ float Xs[64][20], Ys[64][20];
  int tid = threadIdx.x;
  int bi = blockIdx.y, bj = blockIdx.x;
  int ty4 = (tid >> 4)*4, tx4 = (tid & 15)*4;
  int lrow = tid >> 2, lc4 = (tid & 3)*4;
  float acc[4][4] = {{0.f}};
  for (int kc = 0; kc < 512; kc += 16) {
    float4 xa = *(const float4*)(X + (bi*64+lrow)*512 + kc + lc4);
    float4 ya = *(const float4*)(Y + (bj*64+lrow)*512 + kc + lc4);
    Xs[lrow][lc4+0]=xa.x; Xs[lrow][lc4+1]=xa.y; Xs[lrow][lc4+2]=xa.z; Xs[lrow][lc4+3]=xa.w;
    Ys[lrow][lc4+0]=ya.x; Ys[lrow][lc4+1]=ya.y; Ys[lrow][lc4+2]=ya.z; Ys[lrow][lc4+3]=ya.w;
    __syncthreads();
    #pragma unroll
    for (int kk = 0; kk < 16; ++kk) {
      float a0=Xs[ty4+0][kk],a1=Xs[ty4+1][kk],a2=Xs[ty4+2][kk],a3=Xs[ty4+3][kk];
      float b0=Ys[tx4+0][kk],b1=Ys[tx4+1][kk],b2=Ys[tx4+2][kk],b3=Ys[tx4+3][kk];
      FMA16(acc,a0,a1,a2,a3,b0,b1,b2,b3)
    }
    __syncthreads();
  }
  #pragma unroll
  for (int u = 0; u < 4; ++u)
    #pragma unroll
    for (int v = 0; v < 4; ++v) {
      int gi = bi*64+ty4+u, gj = bj*64+tx4+v;
      float o = acc[u][v]; if (gi==gj) o += adiag;
      O[gi*512+gj] = o;
    }
}

// ------------- fused right-looking Cholesky; block b keeps row-block b in LDS
__global__ __launch_bounds__(256) void k_chol_all(float* __restrict__ ws) {
  float* A = ws + OFF_A;
  float* DINV = ws + OFF_DINV;
  unsigned* fD = (unsigned*)(ws + OFF_FLAGS);       // 8: Dinv_p published
  unsigned* fL = fD + 8;                            // 64: fL[j*8+p] Lsub(j,p) published
  __shared__ float R[64*RS];                        // row-block tiles (b,0..b)
  __shared__ float S[64][65];                       // staging: Dinv / Lsub / V out
  __shared__ float TMP[816];
  int tid = threadIdx.x, b = blockIdx.x;
  int ty4 = (tid >> 4)*4, tx4 = (tid & 15)*4;
  int Rb = b*64;
  const int CB = b*64;                              // diag tile column base in R

  // ---- load own row-block into LDS (tiles 0..b)
  for (int tj = 0; tj <= b; ++tj) {
    for (int e = tid*4; e < 4096; e += 1024) {
      int row = e >> 6, col = e & 63;
      float4 g = *(const float4*)(A + (Rb+row)*512 + tj*64 + col);
      float* d = &R[row*RS + tj*64 + col];
      d[0]=g.x; d[1]=g.y; d[2]=g.z; d[3]=g.w;
    }
  }
  __syncthreads();

  // ---- panels p = 0..b-1 (right-looking)
  for (int p = 0; p < b; ++p) {
    int cbp = p*64;
    wait_flag(&fD[p], tid);
    for (int e = tid; e < 4096; e += 256) S[e>>6][e&63] = DINV[p*4096 + e];
    __syncthreads();
    // TRSM in LDS: Lt = G * Dinv_p^T
    float acc[4][4] = {{0.f}};
    for (int m = 0; m < 64; ++m) {
      float a0=R[(ty4+0)*RS+cbp+m],a1=R[(ty4+1)*RS+cbp+m],a2=R[(ty4+2)*RS+cbp+m],a3=R[(ty4+3)*RS+cbp+m];
      float b0=S[tx4+0][m],b1=S[tx4+1][m],b2=S[tx4+2][m],b3=S[tx4+3][m];
      FMA16(acc,a0,a1,a2,a3,b0,b1,b2,b3)
    }
    __syncthreads();   // all reads of G complete before overwrite
    #pragma unroll
    for (int u = 0; u < 4; ++u)
      #pragma unroll
      for (int v = 0; v < 4; ++v) {
        R[(ty4+u)*RS + cbp + tx4+v] = acc[u][v];
        A[(Rb+ty4+u)*512 + cbp + tx4+v] = acc[u][v];
      }
    raise_flag(&fL[b*8+p], tid);                    // includes barrier
    // diag tile update: D -= Lt Lt^T  (own data, disjoint writes)
    {
      float c2[4][4] = {{0.f}};
      for (int m = 0; m < 64; ++m) {
        float a0=R[(ty4+0)*RS+cbp+m],a1=R[(ty4+1)*RS+cbp+m],a2=R[(ty4+2)*RS+cbp+m],a3=R[(ty4+3)*RS+cbp+m];
        float b0=R[(tx4+0)*RS+cbp+m],b1=R[(tx4+1)*RS+cbp+m],b2=R[(tx4+2)*RS+cbp+m],b3=R[(tx4+3)*RS+cbp+m];
        FMA16(c2,a0,a1,a2,a3,b0,b1,b2,b3)
      }
      #pragma unroll
      for (int u = 0; u < 4; ++u)
        #pragma unroll
        for (int v = 0; v < 4; ++v)
          R[(ty4+u)*RS + CB + tx4+v] -= c2[u][v];
    }
    // trailing updates: tiles (b,j), j = p+1..b-1, using published Lsub(j,p)
    for (int j = p+1; j < b; ++j) {
      wait_flag(&fL[j*8+p], tid);                   // barrier separates S reuse
      for (int e = tid; e < 4096; e += 256)
        S[e>>6][e&63] = A[(j*64 + (e>>6))*512 + cbp + (e&63)];
      __syncthreads();
      float c3[4][4] = {{0.f}};
      for (int m = 0; m < 64; ++m) {
        float a0=R[(ty4+0)*RS+cbp+m],a1=R[(ty4+1)*RS+cbp+m],a2=R[(ty4+2)*RS+cbp+m],a3=R[(ty4+3)*RS+cbp+m];
        float b0=S[tx4+0][m],b1=S[tx4+1][m],b2=S[tx4+2][m],b3=S[tx4+3][m];
        FMA16(c3,a0,a1,a2,a3,b0,b1,b2,b3)
      }
      int cbj = j*64;
      #pragma unroll
      for (int u = 0; u < 4; ++u)
        #pragma unroll
        for (int v = 0; v < 4; ++v)
          R[(ty4+u)*RS + cbj + tx4+v] -= c3[u][v];
    }
    __syncthreads();   // writes settled before next panel / factor
  }

  // ---- factor 64x64 diag tile (in R at col CB) via 16-wide sub-panels
  for (int e = tid; e < 4096; e += 256) S[e>>6][e&63] = 0.0f;
  __syncthreads();
  for (int t = 0; t < 4; ++t) {
    const int c0 = t*16;
    if (tid < 16) {
      float a[16];
      #pragma unroll
      for (int j = 0; j < 16; ++j) a[j] = R[(c0+tid)*RS + CB + c0 + j];
      float rr = 0.f;
      #pragma unroll
      for (int j = 0; j < 16; ++j) {
        float d = __shfl(a[j], j);
        float r = rsqrtf(d);
        r = r*(1.5f - 0.5f*d*r*r);
        if (tid == j) rr = r;
        a[j] *= r;
        #pragma unroll
        for (int k = j+1; k < 16; ++k)
          a[k] -= a[j]*__shfl(a[j], k);
      }
      #pragma unroll
      for (int j = 0; j < 16; ++j)
        R[(c0+tid)*RS + CB + c0 + j] = (j <= tid) ? a[j] : 0.0f;
      float v[16];
      #pragma unroll
      for (int i = 0; i < 16; ++i) {
        float s = (tid == i) ? 1.0f : 0.0f;
        #pragma unroll
        for (int k = 0; k < i; ++k)
          s -= R[(c0+i)*RS + CB + c0 + k]*v[k];
        v[i] = s * __shfl(rr, i);
      }
      #pragma unroll
      for (int i = 0; i < 16; ++i)
        S[c0+i][c0+tid] = v[i];
    }
    __syncthreads();
    if (t < 3) {
      const int cnt = 48 - c0;
      const int r0 = c0 + 16;
      float res[3];
      int nout = cnt*16, idx = 0;
      for (int e = tid; e < nout; e += 256, ++idx) {
        int r = r0 + (e >> 4), j = e & 15;
        float s = 0.f;
        #pragma unroll
        for (int m = 0; m < 16; ++m)
          s += R[r*RS + CB + c0 + m]*S[c0+j][c0+m];
        res[idx] = s;
      }
      __syncthreads();
      idx = 0;
      for (int e = tid; e < nout; e += 256, ++idx)
        R[(r0 + (e >> 4))*RS + CB + c0 + (e & 15)] = res[idx];
      __syncthreads();
      for (int e = tid; e < cnt*cnt; e += 256) {
        int r = r0 + e/cnt, c = r0 + e%cnt;
        float s = 0.f;
        #pragma unroll
        for (int m = 0; m < 16; ++m)
          s += R[r*RS + CB + c0 + m]*R[c*RS + CB + c0 + m];
        R[r*RS + CB + c] -= s;
      }
      __syncthreads();
    }
  }
  // assemble off-diag Dinv blocks: V[J][I] = -V_JJ * (sum_k L[J][k] V[k][I])
  for (int d = 1; d < 4; ++d) {
    int nout = (4-d)*256;
    for (int e = tid; e < nout; e += 256) {
      int bs = e >> 8, I = bs, J = I + d;
      int i = (e >> 4) & 15, c = e & 15;
      float s = 0.f;
      for (int k = I; k < J; ++k) {
        #pragma unroll
        for (int m = 0; m < 16; ++m)
          s += R[(J*16+i)*RS + CB + k*16+m]*S[k*16+m][I*16+c];
      }
      TMP[bs*272 + i*17 + c] = s;
    }
    __syncthreads();
    for (int e = tid; e < nout; e += 256) {
      int bs = e >> 8, I = bs, J = I + d;
      int i = (e >> 4) & 15, c = e & 15;
      float s = 0.f;
      #pragma unroll
      for (int m = 0; m < 16; ++m)
        s += S[J*16+i][J*16+m]*TMP[bs*272 + m*17 + c];
      S[J*16+i][I*16+c] = -s;
    }
    __syncthreads();
  }
  for (int e = tid; e < 4096; e += 256)
    DINV[b*4096 + e] = S[e>>6][e&63];
  raise_flag(&fD[b], tid);
}

// ------------- Linv tiles (stored transposed as LT), per-tile flags
__global__ __launch_bounds__(256) void k_linv(float* __restrict__ ws) {
  float* A = ws + OFF_A;
  float* LT = ws + OFF_LINV;
  float* DINV = ws + OFF_DINV;
  unsigned* flg = (unsigned*)(ws + OFF_FLAGS) + 72;
  int tid = threadIdx.x;
  int s = blockIdx.x >> 3, J = blockIdx.x & 7;
  if (s < J) {  // upper of Linv is zero -> LT rows 64J.., cols 64s..
    for (int e = tid; e < 4096; e += 256)
      LT[(64*J + (e>>6))*512 + 64*s + (e&63)] = 0.0f;
    return;
  }
  if (s == J) { // Linv[s][s] = Dinv_s ; store transposed
    for (int e = tid; e < 4096; e += 256) {
      int i = e >> 6, j = e & 63;
      LT[(64*s+j)*512 + 64*s + i] = DINV[s*4096 + e];
    }
    raise_flag(&flg[s*8+J], tid);
    return;
  }
  __shared__ float Ls[64][65];
  __shared__ float Vs[64][65];
  __shared__ float T[64][65];
  __shared__ float Dv[64][65];
  int ty4 = (tid >> 4)*4, tx4 = (tid & 15)*4;
  float acc[4][4] = {{0.f}};
  for (int k = J; k < s; ++k) {
    wait_flag(&flg[k*8+J], tid);
    for (int e = tid; e < 1024; e += 256) {
      int row = e >> 4, m4 = (e & 15)*4;
      float4 a = *(const float4*)(A + (64*s+row)*512 + 64*k + m4);
      Ls[row][m4+0]=a.x; Ls[row][m4+1]=a.y; Ls[row][m4+2]=a.z; Ls[row][m4+3]=a.w;
      float4 v = *(const float4*)(LT + (64*J+row)*512 + 64*k + m4);
      Vs[m4+0][row]=v.x; Vs[m4+1][row]=v.y; Vs[m4+2][row]=v.z; Vs[m4+3][row]=v.w;
    }
    __syncthreads();
    for (int m = 0; m < 64; ++m) {
      float a0=Ls[ty4+0][m],a1=Ls[ty4+1][m],a2=Ls[ty4+2][m],a3=Ls[ty4+3][m];
      float b0=Vs[m][tx4+0],b1=Vs[m][tx4+1],b2=Vs[m][tx4+2],b3=Vs[m][tx4+3];
      FMA16(acc,a0,a1,a2,a3,b0,b1,b2,b3)
    }
    __syncthreads();
  }
  #pragma unroll
  for (int u = 0; u < 4; ++u)
    #pragma unroll
    for (int v = 0; v < 4; ++v)
      T[ty4+u][tx4+v] = acc[u][v];
  for (int e = tid; e < 4096; e += 256) Dv[e>>6][e&63] = DINV[s*4096 + e];
  __syncthreads();
  float acc2[4][4] = {{0.f}};
  for (int m = 0; m < 64; ++m) {
    float a0=Dv[ty4+0][m],a1=Dv[ty4+1][m],a2=Dv[ty4+2][m],a3=Dv[ty4+3][m];
    float b0=T[m][tx4+0],b1=T[m][tx4+1],b2=T[m][tx4+2],b3=T[m][tx4+3];
    FMA16(acc2,a0,a1,a2,a3,b0,b1,b2,b3)
  }
  #pragma unroll
  for (int u = 0; u < 4; ++u)
    #pragma unroll
    for (int v = 0; v < 4; ++v)
      LT[(64*J+tx4+v)*512 + 64*s+ty4+u] = -acc2[u][v];
  raise_flag(&flg[s*8+J], tid);
}

// --------------------- w = Linv^T q_mu  (w[c] = sum_r LT[c][r] qmu[r])
__global__ __launch_bounds__(256) void k_wvec(const float* __restrict__ qmu,
                                              float* __restrict__ ws) {
  const float* LT = ws + OFF_LINV;
  float* W = ws + OFF_W;
  __shared__ float part[256];
  int tid = threadIdx.x;
  int c = blockIdx.x*64 + (tid >> 2);
  int q = tid & 3;
  float acc = 0.f;
  for (int r = q*128; r < q*128 + 128; r += 4) {
    float4 v = *(const float4*)(LT + c*512 + r);
    float4 m = *(const float4*)(qmu + r);
    acc += v.x*m.x + v.y*m.y + v.z*m.z + v.w*m.w;
  }
  part[tid] = acc;
  __syncthreads();
  if (q == 0) W[c] = part[tid]+part[tid+1]+part[tid+2]+part[tid+3];
}

// --------------------- main: per-point quadratic forms + ell partials
__global__ __launch_bounds__(256) void k_main(const float* __restrict__ X,
    const float* __restrict__ Yv, const float* __restrict__ Z,
    const float* __restrict__ llvP, const float* __restrict__ lsP,
    const float* __restrict__ osP, float* __restrict__ ws) {
  const float* LT = ws + OFF_LINV;
  const float* QC = ws + OFF_QC;
  const float* W = ws + OFF_W;
  float* PART = ws + OFF_PART;
  __shared__ float KL[8192];      // [c][pt] 512 x 16 : k tile, then l tile
  __shared__ float RD[2176];      // 2 x 64x17 reduction scratch
  __shared__ float wsh[512];
  __shared__ float Xs[16][8];
  __shared__ float pmv[16], lsqv[16], elli[16];
  int tid = threadIdx.x, B = blockIdx.x;
  float ls = lsP[0], os = osP[0], llv = llvP[0];
  float ils2 = 1.0f/(ls*ls);
  if (tid < 128) { int pp = tid>>3, d = tid&7; Xs[pp][d] = X[(B*16+pp)*8 + d]; }
  wsh[tid] = W[tid]; wsh[tid+256] = W[tid+256];
  __syncthreads();
  for (int e = tid; e < 8192; e += 256) {
    int cc = e >> 4, pp = e & 15;
    float4 z0 = *(const float4*)(Z + cc*8);
    float4 z1 = *(const float4*)(Z + cc*8 + 4);
    float d0=z0.x-Xs[pp][0], d1=z0.y-Xs[pp][1], d2=z0.z-Xs[pp][2], d3=z0.w-Xs[pp][3];
    float d4=z1.x-Xs[pp][4], d5=z1.y-Xs[pp][5], d6=z1.z-Xs[pp][6], d7=z1.w-Xs[pp][7];
    float sq = d0*d0+d1*d1+d2*d2+d3*d3+d4*d4+d5*d5+d6*d6+d7*d7;
    KL[e] = os*__expf(-0.5f*ils2*sq);
  }
  __syncthreads();
  int rq = tid >> 2;
  int rq4 = rq*4, pq4 = (tid & 3)*4;
  // phase A: l[r][pt] = sum_c LT[c][r] * k[c][pt]
  float acc0[4][4] = {{0.f}}, acc1[4][4] = {{0.f}};
  #pragma unroll 4
  for (int c = 0; c < 256; ++c) {
    float4 kv = *(const float4*)&KL[c*16 + pq4];
    float4 l0 = *(const float4*)(LT + c*512 + rq4);
    float4 l1 = *(const float4*)(LT + c*512 + 256 + rq4);
    FMA16(acc0, l0.x,l0.y,l0.z,l0.w, kv.x,kv.y,kv.z,kv.w)
    FMA16(acc1, l1.x,l1.y,l1.z,l1.w, kv.x,kv.y,kv.z,kv.w)
  }
  #pragma unroll 4
  for (int c = 256; c < 512; ++c) {
    float4 kv = *(const float4*)&KL[c*16 + pq4];
    float4 l1 = *(const float4*)(LT + c*512 + 256 + rq4);
    FMA16(acc1, l1.x,l1.y,l1.z,l1.w, kv.x,kv.y,kv.z,kv.w)
  }
  // pred-mean partials (KL still holds k) and ||l||^2 partials
  float pmp[4] = {0.f,0.f,0.f,0.f};
  for (int c8 = 0; c8 < 8; ++c8) {
    int cc2 = rq*8 + c8;
    float wv = wsh[cc2];
    pmp[0] += KL[cc2*16+pq4+0]*wv; pmp[1] += KL[cc2*16+pq4+1]*wv;
    pmp[2] += KL[cc2*16+pq4+2]*wv; pmp[3] += KL[cc2*16+pq4+3]*wv;
  }
  float lsp[4] = {0.f,0.f,0.f,0.f};
  #pragma unroll
  for (int u = 0; u < 4; ++u)
    #pragma unroll
    for (int v = 0; v < 4; ++v)
      lsp[v] += acc0[u][v]*acc0[u][v] + acc1[u][v]*acc1[u][v];
  #pragma unroll
  for (int v = 0; v < 4; ++v) {
    RD[rq*17 + pq4+v] = pmp[v];
    RD[1088 + rq*17 + pq4+v] = lsp[v];
  }
  __syncthreads();
  if (tid < 16) {
    float a = 0.f, b = 0.f;
    for (int r2 = 0; r2 < 64; ++r2) { a += RD[r2*17+tid]; b += RD[1088+r2*17+tid]; }
    pmv[tid] = a; lsqv[tid] = b;
  }
  __syncthreads();
  // overwrite KL with l
  #pragma unroll
  for (int u = 0; u < 4; ++u) {
    *(float4*)&KL[(rq4+u)*16 + pq4] = make_float4(acc0[u][0],acc0[u][1],acc0[u][2],acc0[u][3]);
    *(float4*)&KL[(256+rq4+u)*16 + pq4] = make_float4(acc1[u][0],acc1[u][1],acc1[u][2],acc1[u][3]);
  }
  __syncthreads();
  // phase B: u = QC @ l (QC symmetric -> row access), accumulate ||u||^2
  float ua0[4][4] = {{0.f}}, ua1[4][4] = {{0.f}};
  #pragma unroll 4
  for (int c = 0; c < 512; ++c) {
    float4 kv = *(const float4*)&KL[c*16 + pq4];
    float4 q0 = *(const float4*)(QC + c*512 + rq4);
    float4 q1 = *(const float4*)(QC + c*512 + 256 + rq4);
    FMA16(ua0, q0.x,q0.y,q0.z,q0.w, kv.x,kv.y,kv.z,kv.w)
    FMA16(ua1, q1.x,q1.y,q1.z,q1.w, kv.x,kv.y,kv.z,kv.w)
  }
  float usq[4] = {0.f,0.f,0.f,0.f};
  #pragma unroll
  for (int u = 0; u < 4; ++u)
    #pragma unroll
    for (int v = 0; v < 4; ++v)
      usq[v] += ua0[u][v]*ua0[u][v] + ua1[u][v]*ua1[u][v];
  #pragma unroll
  for (int v = 0; v < 4; ++v) RD[rq*17 + pq4+v] = usq[v];
  __syncthreads();
  if (tid < 16) {
    float us = 0.f;
    for (int r2 = 0; r2 < 64; ++r2) us += RD[r2*17+tid];
    int gi = B*16 + tid;
    float diff = Yv[gi] - pmv[tid];
    float diagc = os + us - lsqv[tid];
    float iss = __expf(-llv);
    elli[tid] = -0.5f*((diff*diff + diagc)*iss + (LOG2PI + llv));
  }
  __syncthreads();
  if (tid == 0) {
    float s = 0.f;
    #pragma unroll
    for (int i2 = 0; i2 < 16; ++i2) s += elli[i2];
    PART[B] = s;
  }
}

// --------------------- final scalar
__global__ __launch_bounds__(256) void k_final(const float* __restrict__ qmu,
    const float* __restrict__ qlv, float* __restrict__ ws, float* __restrict__ out) {
  __shared__ double sh[256];
  int tid = threadIdx.x;
  const float* QC = ws + OFF_QC;
  const float* PART = ws + OFF_PART;
  double pa = 0.0, tr = 0.0, mm = 0.0, ld = 0.0;
  for (int i = tid; i < 512; i += 256) {
    pa += (double)PART[i];
    tr += (double)QC[i*513];
    double q = (double)qmu[i]; mm += q*q;
    ld += (double)qlv[i*513];
  }
  double vals[4] = {pa, tr, mm, ld};
  double res[4];
  for (int t2 = 0; t2 < 4; ++t2) {
    sh[tid] = vals[t2]; __syncthreads();
    for (int s2 = 128; s2 > 0; s2 >>= 1) {
      if (tid < s2) sh[tid] += sh[tid+s2];
      __syncthreads();
    }
    res[t2] = sh[0]; __syncthreads();
  }
  if (tid == 0) {
    double n = 8192.0;
    double ell = res[0]/n;
    double kl = 0.5*(res[1] + res[2] - 512.0 - res[3])/n;
    out[0] = (float)(ell - kl);
  }
}

extern "C" void kernel_launch(void* const* d_in, const int* in_sizes, int n_in,
                              void* d_out, int out_size, void* d_ws, size_t ws_size,
                              hipStream_t stream) {
  (void)in_sizes; (void)n_in; (void)out_size; (void)ws_size;
  const float* X   = (const float*)d_in[0];
  const float* Y   = (const float*)d_in[1];
  const float* Z   = (const float*)d_in[2];
  const float* qmu = (const float*)d_in[3];
  const float* qlv = (const float*)d_in[4];
  const float* llv = (const float*)d_in[5];
  const float* ls  = (const float*)d_in[6];
  const float* os  = (const float*)d_in[7];
  float* ws = (float*)d_ws;
  float* out = (float*)d_out;

  k_prep<<<2048, 256, 0, stream>>>(Z, qlv, ls, os, ws);
  k_gemm_nt<<<dim3(8,8), 256, 0, stream>>>(ws+OFF_QS, ws+OFF_QS, ws+OFF_QC, JIT);
  k_chol_all<<<8, 256, 0, stream>>>(ws);
  k_linv<<<64, 256, 0, stream>>>(ws);
  k_wvec<<<8, 256, 0, stream>>>(qmu, ws);
  k_main<<<512, 256, 0, stream>>>(X, Y, Z, llv, ls, os, ws);
  k_final<<<1, 256, 0, stream>>>(qmu, qlv, ws, out);
}

// Round 8
// 463.766 us; speedup vs baseline: 2.8474x; 1.2097x over previous
//
#include <hip/hip_runtime.h>
#include <math.h>

#define MI 512
#define NPT 8192
#define JIT 1e-6f
#define LOG2PI 1.8378770664093453f

// ws float offsets
#define OFF_A     0         // 512x512 Kuu -> L (lower; diag blocks never read downstream)
#define OFF_LINV  262144    // 512x512 Linv^T (LT[r][c] = Linv[c][r]); upper region unused
#define OFF_QS    524288    // 512x512 q_sqrt
#define OFF_QC    786432    // 512x512 q_cov (symmetric)
#define OFF_DINV  1048576   // 8 x 64x64 diag-block inverses
#define OFF_PART  1081856   // 512 block partial ell sums
#define OFF_FLAGS 1082368   // [0..7] fD, [8..71] fL(b*8+p), [72..135] TFLG(s*8+J), [136..143] rowcnt

#define FMA16(ACC,a0,a1,a2,a3,b0,b1,b2,b3) \
  ACC[0][0]+=a0*b0; ACC[0][1]+=a0*b1; ACC[0][2]+=a0*b2; ACC[0][3]+=a0*b3; \
  ACC[1][0]+=a1*b0; ACC[1][1]+=a1*b1; ACC[1][2]+=a1*b2; ACC[1][3]+=a1*b3; \
  ACC[2][0]+=a2*b0; ACC[2][1]+=a2*b1; ACC[2][2]+=a2*b2; ACC[2][3]+=a2*b3; \
  ACC[3][0]+=a3*b0; ACC[3][1]+=a3*b1; ACC[3][2]+=a3*b2; ACC[3][3]+=a3*b3;

__device__ __forceinline__ void wait_flag(unsigned* f, int tid) {
  if (tid == 0) {
    while (__hip_atomic_load(f, __ATOMIC_RELAXED, __HIP_MEMORY_SCOPE_AGENT) == 0)
      __builtin_amdgcn_s_sleep(2);
    __builtin_amdgcn_fence(__ATOMIC_ACQUIRE, "agent");
  }
  __syncthreads();
}
__device__ __forceinline__ void wait_count(unsigned* c, unsigned tgt, int tid) {
  if (tid == 0) {
    while (__hip_atomic_load(c, __ATOMIC_RELAXED, __HIP_MEMORY_SCOPE_AGENT) < tgt)
      __builtin_amdgcn_s_sleep(2);
    __builtin_amdgcn_fence(__ATOMIC_ACQUIRE, "agent");
  }
  __syncthreads();
}
__device__ __forceinline__ void raise_flag(unsigned* f, int tid) {
  __syncthreads();
  if (tid == 0) {
    __builtin_amdgcn_fence(__ATOMIC_RELEASE, "agent");
    __hip_atomic_store(f, 1u, __ATOMIC_RELAXED, __HIP_MEMORY_SCOPE_AGENT);
  }
}
__device__ __forceinline__ void publish_tile(unsigned* f, unsigned* cnt, int tid) {
  __syncthreads();
  if (tid == 0) {
    __builtin_amdgcn_fence(__ATOMIC_RELEASE, "agent");
    __hip_atomic_store(f, 1u, __ATOMIC_RELAXED, __HIP_MEMORY_SCOPE_AGENT);
    __hip_atomic_fetch_add(cnt, 1u, __ATOMIC_RELAXED, __HIP_MEMORY_SCOPE_AGENT);
  }
}

// ---------------------------------------------------------------- prep
__global__ __launch_bounds__(256) void k_prep(const float* __restrict__ Z,
    const float* __restrict__ qlv, const float* __restrict__ lsP,
    const float* __restrict__ osP, float* __restrict__ ws) {
  int u = blockIdx.x*256 + threadIdx.x;
  if (blockIdx.x == 0 && threadIdx.x < 160)
    ((unsigned*)(ws + OFF_FLAGS))[threadIdx.x] = 0u;
  float ls = lsP[0], os = osP[0];
  float ils2 = 1.0f/(ls*ls);
  if (u < MI*MI) {
    int i = u >> 9, j = u & 511;
    float4 a0 = *(const float4*)(Z + i*8);
    float4 a1 = *(const float4*)(Z + i*8 + 4);
    float4 b0 = *(const float4*)(Z + j*8);
    float4 b1 = *(const float4*)(Z + j*8 + 4);
    float d0=a0.x-b0.x, d1=a0.y-b0.y, d2=a0.z-b0.z, d3=a0.w-b0.w;
    float d4=a1.x-b1.x, d5=a1.y-b1.y, d6=a1.z-b1.z, d7=a1.w-b1.w;
    float sq = d0*d0+d1*d1+d2*d2+d3*d3+d4*d4+d5*d5+d6*d6+d7*d7;
    float v = os*__expf(-0.5f*ils2*sq);
    if (i==j) v += JIT;
    ws[OFF_A + u] = v;
  } else {
    int w2 = u - MI*MI;
    if (w2 < MI*MI) {
      int i = w2 >> 9, j = w2 & 511;
      ws[OFF_QS + w2] = (j <= i) ? __expf(0.5f*qlv[w2]) : 0.0f;
    }
  }
}

// ------------------------------------------------- O = X Y^T + adiag*I (K=512)
__global__ __launch_bounds__(256) void k_gemm_nt(const float* __restrict__ X,
    const float* __restrict__ Y, float* __restrict__ O, float adiag) {
  __shared__ float Xs[64][20], Ys[64][20];
  int tid = threadIdx.x;
  int bi = blockIdx.y, bj = blockIdx.x;
  int ty4 = (tid >> 4)*4, tx4 = (tid & 15)*4;
  int lrow = tid >> 2, lc4 = (tid & 3)*4;
  float acc[4][4] = {{0.f}};
  for (int kc = 0; kc < 512; kc += 16) {
    float4 xa = *(const float4*)(X + (bi*64+lrow)*512 + kc + lc4);
    float4 ya = *(const float4*)(Y + (bj*64+lrow)*512 + kc + lc4);
    Xs[lrow][lc4+0]=xa.x; Xs[lrow][lc4+1]=xa.y; Xs[lrow][lc4+2]=xa.z; Xs[lrow][lc4+3]=xa.w;
    Ys[lrow][lc4+0]=ya.x; Ys[lrow][lc4+1]=ya.y; Ys[lrow][lc4+2]=ya.z; Ys[lrow][lc4+3]=ya.w;
    __syncthreads();
    #pragma unroll
    for (int kk = 0; kk < 16; ++kk) {
      float a0=Xs[ty4+0][kk],a1=Xs[ty4+1][kk],a2=Xs[ty4+2][kk],a3=Xs[ty4+3][kk];
      float b0=Ys[tx4+0][kk],b1=Ys[tx4+1][kk],b2=Ys[tx4+2][kk],b3=Ys[tx4+3][kk];
      FMA16(acc,a0,a1,a2,a3,b0,b1,b2,b3)
    }
    __syncthreads();
  }
  #pragma unroll
  for (int u = 0; u < 4; ++u)
    #pragma unroll
    for (int v = 0; v < 4; ++v) {
      int gi = bi*64+ty4+u, gj = bj*64+tx4+v;
      float o = acc[u][v]; if (gi==gj) o += adiag;
      O[gi*512+gj] = o;
    }
}

// ---------------- fused DAG: chol(8) + linv(36) + main(512) in one kernel
__global__ __launch_bounds__(256) void k_dag(const float* __restrict__ X,
    const float* __restrict__ Yv, const float* __restrict__ Z,
    const float* __restrict__ qmu, const float* __restrict__ llvP,
    const float* __restrict__ lsP, const float* __restrict__ osP,
    float* __restrict__ ws) {
  __shared__ float SH[13400];   // 53.6 KB uniform -> 3 blocks/CU
  float* A    = ws + OFF_A;
  float* LT   = ws + OFF_LINV;
  const float* QC = ws + OFF_QC;
  float* DINV = ws + OFF_DINV;
  float* PART = ws + OFF_PART;
  unsigned* FLG  = (unsigned*)(ws + OFF_FLAGS);   // fD
  unsigned* FL   = FLG + 8;                       // fL[b*8+p]
  unsigned* TFLG = FLG + 72;                      // linv tile flags [s*8+J]
  unsigned* ROWC = FLG + 136;                     // rowcnt[s]
  int bid = blockIdx.x, tid = threadIdx.x;
  int ty4 = (tid >> 4)*4, tx4 = (tid & 15)*4;

  // ================= CHOL path (left-looking, late fD wait) ==============
  if (bid < 8) {
    int b = bid, Rb = b*64;
    float* Dg = SH;            // [64][65] running diag tile
    float* Sa = SH + 4160;     // staging A / Dinv / assembly target
    float* Sb = SH + 8320;     // staging B / G / Lsub
    float* TMP = SH + 12480;   // 816 floats
    for (int e = tid; e < 4096; e += 256)
      Dg[(e>>6)*65 + (e&63)] = A[(Rb + (e>>6))*512 + Rb + (e&63)];

    for (int p = 0; p < b; ++p) {
      // gram: gacc = sum_{pp<p} Lsub(b,pp) Lsub(p,pp)^T  (off the fD chain)
      float gacc[4][4] = {{0.f}};
      for (int pp = 0; pp < p; ++pp) {
        wait_flag(&FL[p*8+pp], tid);      // other row's tile; barrier guards restage
        for (int e = tid; e < 4096; e += 256) {
          int row = e>>6, col = e&63;
          Sa[row*65+col] = A[(Rb+row)*512 + pp*64 + col];      // Lsub(b,pp), own
          Sb[row*65+col] = A[(p*64+row)*512 + pp*64 + col];    // Lsub(p,pp)
        }
        __syncthreads();
        for (int m = 0; m < 64; ++m) {
          float a0=Sa[(ty4+0)*65+m],a1=Sa[(ty4+1)*65+m],a2=Sa[(ty4+2)*65+m],a3=Sa[(ty4+3)*65+m];
          float b0=Sb[(tx4+0)*65+m],b1=Sb[(tx4+1)*65+m],b2=Sb[(tx4+2)*65+m],b3=Sb[(tx4+3)*65+m];
          FMA16(gacc,a0,a1,a2,a3,b0,b1,b2,b3)
        }
      }
      wait_flag(&FLG[p], tid);            // fD[p]; barrier guards Sa/Sb reuse
      // G = A0(b,p) - gacc -> Sb ; Dinv_p -> Sa
      for (int e = tid; e < 4096; e += 256)
        Sa[(e>>6)*65 + (e&63)] = DINV[p*4096 + e];
      #pragma unroll
      for (int u = 0; u < 4; ++u)
        #pragma unroll
        for (int v = 0; v < 4; ++v)
          Sb[(ty4+u)*65 + tx4+v] = A[(Rb+ty4+u)*512 + p*64 + tx4+v] - gacc[u][v];
      __syncthreads();
      // TRSM: Lsub = G * Dinv_p^T
      float acc2[4][4] = {{0.f}};
      for (int m = 0; m < 64; ++m) {
        float a0=Sb[(ty4+0)*65+m],a1=Sb[(ty4+1)*65+m],a2=Sb[(ty4+2)*65+m],a3=Sb[(ty4+3)*65+m];
        float b0=Sa[(tx4+0)*65+m],b1=Sa[(tx4+1)*65+m],b2=Sa[(tx4+2)*65+m],b3=Sa[(tx4+3)*65+m];
        FMA16(acc2,a0,a1,a2,a3,b0,b1,b2,b3)
      }
      __syncthreads();                    // G reads complete before overwrite
      #pragma unroll
      for (int u = 0; u < 4; ++u)
        #pragma unroll
        for (int v = 0; v < 4; ++v) {
          Sb[(ty4+u)*65 + tx4+v] = acc2[u][v];
          A[(Rb+ty4+u)*512 + p*64 + tx4+v] = acc2[u][v];
        }
      raise_flag(&FL[b*8+p], tid);        // release: Lsub(b,p) visible
      // SYRK: Dg -= Lsub Lsub^T
      float c2[4][4] = {{0.f}};
      for (int m = 0; m < 64; ++m) {
        float a0=Sb[(ty4+0)*65+m],a1=Sb[(ty4+1)*65+m],a2=Sb[(ty4+2)*65+m],a3=Sb[(ty4+3)*65+m];
        float b0=Sb[(tx4+0)*65+m],b1=Sb[(tx4+1)*65+m],b2=Sb[(tx4+2)*65+m],b3=Sb[(tx4+3)*65+m];
        FMA16(c2,a0,a1,a2,a3,b0,b1,b2,b3)
      }
      #pragma unroll
      for (int u = 0; u < 4; ++u)
        #pragma unroll
        for (int v = 0; v < 4; ++v)
          Dg[(ty4+u)*65 + tx4+v] -= c2[u][v];
    }
    __syncthreads();

    // factor 64x64 Dg via 16-wide sub-panels; Dinv assembled into Sa
    for (int e = tid; e < 4096; e += 256) Sa[(e>>6)*65 + (e&63)] = 0.0f;
    __syncthreads();
    for (int t = 0; t < 4; ++t) {
      const int c0 = t*16;
      if (tid < 16) {
        float a[16];
        #pragma unroll
        for (int j = 0; j < 16; ++j) a[j] = Dg[(c0+tid)*65 + c0 + j];
        float rr = 0.f;
        #pragma unroll
        for (int j = 0; j < 16; ++j) {
          float d = __shfl(a[j], j);
          float r = rsqrtf(d);
          r = r*(1.5f - 0.5f*d*r*r);
          if (tid == j) rr = r;
          a[j] *= r;
          #pragma unroll
          for (int k = j+1; k < 16; ++k)
            a[k] -= a[j]*__shfl(a[j], k);
        }
        #pragma unroll
        for (int j = 0; j < 16; ++j)
          Dg[(c0+tid)*65 + c0 + j] = (j <= tid) ? a[j] : 0.0f;
        float v[16];
        #pragma unroll
        for (int i = 0; i < 16; ++i) {
          float s = (tid == i) ? 1.0f : 0.0f;
          #pragma unroll
          for (int k = 0; k < i; ++k)
            s -= Dg[(c0+i)*65 + c0 + k]*v[k];
          v[i] = s * __shfl(rr, i);
        }
        #pragma unroll
        for (int i = 0; i < 16; ++i)
          Sa[(c0+i)*65 + c0 + tid] = v[i];
      }
      __syncthreads();
      if (t < 3) {
        const int cnt = 48 - c0;
        const int r0 = c0 + 16;
        float res[3];
        int nout = cnt*16, idx = 0;
        for (int e = tid; e < nout; e += 256, ++idx) {
          int r = r0 + (e >> 4), j = e & 15;
          float s = 0.f;
          #pragma unroll
          for (int m = 0; m < 16; ++m)
            s += Dg[r*65 + c0 + m]*Sa[(c0+j)*65 + c0 + m];
          res[idx] = s;
        }
        __syncthreads();
        idx = 0;
        for (int e = tid; e < nout; e += 256, ++idx)
          Dg[(r0 + (e >> 4))*65 + c0 + (e & 15)] = res[idx];
        __syncthreads();
        for (int e = tid; e < cnt*cnt; e += 256) {
          int r = r0 + e/cnt, c = r0 + e%cnt;
          float s = 0.f;
          #pragma unroll
          for (int m = 0; m < 16; ++m)
            s += Dg[r*65 + c0 + m]*Dg[c*65 + c0 + m];
          Dg[r*65 + c] -= s;
        }
        __syncthreads();
      }
    }
    for (int d = 1; d < 4; ++d) {
      int nout = (4-d)*256;
      for (int e = tid; e < nout; e += 256) {
        int bs = e >> 8, I = bs, J = I + d;
        int i = (e >> 4) & 15, c = e & 15;
        float s = 0.f;
        for (int k = I; k < J; ++k) {
          #pragma unroll
          for (int m = 0; m < 16; ++m)
            s += Dg[(J*16+i)*65 + k*16+m]*Sa[(k*16+m)*65 + I*16+c];
        }
        TMP[bs*272 + i*17 + c] = s;
      }
      __syncthreads();
      for (int e = tid; e < nout; e += 256) {
        int bs = e >> 8, I = bs, J = I + d;
        int i = (e >> 4) & 15, c = e & 15;
        float s = 0.f;
        #pragma unroll
        for (int m = 0; m < 16; ++m)
          s += Sa[(J*16+i)*65 + J*16+m]*TMP[bs*272 + m*17 + c];
        Sa[(J*16+i)*65 + I*16+c] = -s;
      }
      __syncthreads();
    }
    for (int e = tid; e < 4096; e += 256)
      DINV[b*4096 + e] = Sa[(e>>6)*65 + (e&63)];
    raise_flag(&FLG[b], tid);             // fD[b]
    return;
  }

  // ================= LINV path (36 lower-tri tiles) ======================
  if (bid < 44) {
    int t = bid - 8;
    int s = 0, rem = t;
    while (rem >= s+1) { rem -= (s+1); ++s; }
    int J = rem;                          // tile (s,J), J<=s
    if (s == J) {                         // Linv[s][s] = Dinv_s, store transposed
      wait_flag(&FLG[s], tid);
      for (int e = tid; e < 4096; e += 256) {
        int i = e >> 6, j = e & 63;
        LT[(64*s+j)*512 + 64*s + i] = DINV[s*4096 + e];
      }
      publish_tile(&TFLG[s*8+J], &ROWC[s], tid);
      return;
    }
    float* Ls = SH;            // [64][65]; later reused as Dv
    float* Vs = SH + 4160;     // [64][65]
    float* T  = SH + 8320;     // [64][65]
    float acc[4][4] = {{0.f}};
    for (int k = J; k < s; ++k) {
      wait_flag(&TFLG[k*8+J], tid);       // LT(k,J) ready
      wait_flag(&FL[s*8+k], tid);         // Lsub(s,k) ready
      for (int e = tid; e < 1024; e += 256) {
        int row = e >> 4, m4 = (e & 15)*4;
        float4 a = *(const float4*)(A + (64*s+row)*512 + 64*k + m4);
        Ls[row*65+m4+0]=a.x; Ls[row*65+m4+1]=a.y; Ls[row*65+m4+2]=a.z; Ls[row*65+m4+3]=a.w;
        float4 v = *(const float4*)(LT + (64*J+row)*512 + 64*k + m4);
        Vs[(m4+0)*65+row]=v.x; Vs[(m4+1)*65+row]=v.y; Vs[(m4+2)*65+row]=v.z; Vs[(m4+3)*65+row]=v.w;
      }
      __syncthreads();
      for (int m = 0; m < 64; ++m) {
        float a0=Ls[(ty4+0)*65+m],a1=Ls[(ty4+1)*65+m],a2=Ls[(ty4+2)*65+m],a3=Ls[(ty4+3)*65+m];
        float b0=Vs[m*65+tx4+0],b1=Vs[m*65+tx4+1],b2=Vs[m*65+tx4+2],b3=Vs[m*65+tx4+3];
        FMA16(acc,a0,a1,a2,a3,b0,b1,b2,b3)
      }
      __syncthreads();
    }
    wait_flag(&FLG[s], tid);              // fD[s] for DINV[s]; barriers Ls reuse
    #pragma unroll
    for (int u = 0; u < 4; ++u)
      #pragma unroll
      for (int v = 0; v < 4; ++v)
        T[(ty4+u)*65 + tx4+v] = acc[u][v];
    for (int e = tid; e < 4096; e += 256) Ls[(e>>6)*65 + (e&63)] = DINV[s*4096 + e];
    __syncthreads();
    float acc2[4][4] = {{0.f}};
    for (int m = 0; m < 64; ++m) {
      float a0=Ls[(ty4+0)*65+m],a1=Ls[(ty4+1)*65+m],a2=Ls[(ty4+2)*65+m],a3=Ls[(ty4+3)*65+m];
      float b0=T[m*65+tx4+0],b1=T[m*65+tx4+1],b2=T[m*65+tx4+2],b3=T[m*65+tx4+3];
      FMA16(acc2,a0,a1,a2,a3,b0,b1,b2,b3)
    }
    #pragma unroll
    for (int u = 0; u < 4; ++u)
      #pragma unroll
      for (int v = 0; v < 4; ++v)
        LT[(64*J+tx4+v)*512 + 64*s+ty4+u] = -acc2[u][v];
    publish_tile(&TFLG[s*8+J], &ROWC[s], tid);
    return;
  }

  // ================= MAIN path (512 blocks, slab-gated) ==================
  {
    int B = bid - 44;
    float* KL  = SH;            // 8192: k[c][pt] stride 16 (kept intact)
    float* Lst = SH + 8192;     // 1280: l-slab staging [r_local][pt] stride 20
    float* RD  = SH + 9472;     // 2176
    float* qsh = SH + 11648;    // 512
    float* Xs  = SH + 12160;    // 128 (16x8)
    float* pmv = SH + 12288;    // 16
    float* lsqv= SH + 12304;    // 16
    float* elli= SH + 12320;    // 16
    float ls = lsP[0], os = osP[0], llv = llvP[0];
    float ils2 = 1.0f/(ls*ls);
    if (tid < 128) { int pp = tid>>3, d = tid&7; Xs[pp*8+d] = X[(B*16+pp)*8 + d]; }
    qsh[tid] = qmu[tid]; qsh[tid+256] = qmu[tid+256];
    __syncthreads();
    for (int e = tid; e < 8192; e += 256) {
      int cc = e >> 4, pp = e & 15;
      float4 z0 = *(const float4*)(Z + cc*8);
      float4 z1 = *(const float4*)(Z + cc*8 + 4);
      float d0=z0.x-Xs[pp*8+0], d1=z0.y-Xs[pp*8+1], d2=z0.z-Xs[pp*8+2], d3=z0.w-Xs[pp*8+3];
      float d4=z1.x-Xs[pp*8+4], d5=z1.y-Xs[pp*8+5], d6=z1.z-Xs[pp*8+6], d7=z1.w-Xs[pp*8+7];
      float sq = d0*d0+d1*d1+d2*d2+d3*d3+d4*d4+d5*d5+d6*d6+d7*d7;
      KL[e] = os*__expf(-0.5f*ils2*sq);
    }
    __syncthreads();
    int rq = tid >> 2, rq4 = rq*4, pq4 = (tid & 3)*4;
    int sl = tid >> 6;                      // this thread's slab within each half
    float ua0[4][4] = {{0.f}}, ua1[4][4] = {{0.f}};
    float pmp[4] = {0.f,0.f,0.f,0.f}, lsp[4] = {0.f,0.f,0.f,0.f};
    for (int s = 0; s < 8; ++s) {
      wait_count(&ROWC[s], (unsigned)(s+1), tid);
      int active = (s < 4) ? (sl == s) : (sl == s-4);
      if (active) {
        float acc[4][4] = {{0.f}};
        const float* Lbase = LT + ((s < 4) ? rq4 : (256 + rq4));
        int clen = 64*(s+1);
        #pragma unroll 4
        for (int c = 0; c < clen; ++c) {
          float4 kv = *(const float4*)&KL[c*16 + pq4];
          float4 l0 = *(const float4*)(Lbase + c*512);
          FMA16(acc, l0.x,l0.y,l0.z,l0.w, kv.x,kv.y,kv.z,kv.w)
        }
        int rg = (s < 4) ? rq4 : (256 + rq4);           // global r of acc row 0
        int rl4 = rg - s*64;                             // local row in slab
        #pragma unroll
        for (int u = 0; u < 4; ++u) {
          float q = qsh[rg + u];
          #pragma unroll
          for (int v = 0; v < 4; ++v) {
            pmp[v] += acc[u][v]*q;
            lsp[v] += acc[u][v]*acc[u][v];
            Lst[(rl4+u)*20 + pq4+v] = acc[u][v];
          }
        }
      }
      __syncthreads();
      // phase B contribution of this c-slab: u += QC[:,slab] * l_slab
      for (int cl = 0; cl < 64; ++cl) {
        float4 kv = *(const float4*)&Lst[cl*20 + pq4];
        float4 q0 = *(const float4*)(QC + (64*s+cl)*512 + rq4);
        float4 q1 = *(const float4*)(QC + (64*s+cl)*512 + 256 + rq4);
        FMA16(ua0, q0.x,q0.y,q0.z,q0.w, kv.x,kv.y,kv.z,kv.w)
        FMA16(ua1, q1.x,q1.y,q1.z,q1.w, kv.x,kv.y,kv.z,kv.w)
      }
      __syncthreads();                       // before Lst reuse next slab
    }
    // reductions
    #pragma unroll
    for (int v = 0; v < 4; ++v) {
      RD[rq*17 + pq4+v] = pmp[v];
      RD[1088 + rq*17 + pq4+v] = lsp[v];
    }
    __syncthreads();
    if (tid < 16) {
      float a = 0.f, b2 = 0.f;
      for (int r2 = 0; r2 < 64; ++r2) { a += RD[r2*17+tid]; b2 += RD[1088+r2*17+tid]; }
      pmv[tid] = a; lsqv[tid] = b2;
    }
    __syncthreads();
    float usq[4] = {0.f,0.f,0.f,0.f};
    #pragma unroll
    for (int u = 0; u < 4; ++u)
      #pragma unroll
      for (int v = 0; v < 4; ++v)
        usq[v] += ua0[u][v]*ua0[u][v] + ua1[u][v]*ua1[u][v];
    #pragma unroll
    for (int v = 0; v < 4; ++v) RD[rq*17 + pq4+v] = usq[v];
    __syncthreads();
    if (tid < 16) {
      float us = 0.f;
      for (int r2 = 0; r2 < 64; ++r2) us += RD[r2*17+tid];
      int gi = B*16 + tid;
      float diff = Yv[gi] - pmv[tid];
      float diagc = os + us - lsqv[tid];
      float iss = __expf(-llv);
      elli[tid] = -0.5f*((diff*diff + diagc)*iss + (LOG2PI + llv));
    }
    __syncthreads();
    if (tid == 0) {
      float sum = 0.f;
      #pragma unroll
      for (int i2 = 0; i2 < 16; ++i2) sum += elli[i2];
      PART[B] = sum;
    }
  }
}

// --------------------- final scalar
__global__ __launch_bounds__(256) void k_final(const float* __restrict__ qmu,
    const float* __restrict__ qlv, float* __restrict__ ws, float* __restrict__ out) {
  __shared__ double sh[256];
  int tid = threadIdx.x;
  const float* QC = ws + OFF_QC;
  const float* PART = ws + OFF_PART;
  double pa = 0.0, tr = 0.0, mm = 0.0, ld = 0.0;
  for (int i = tid; i < 512; i += 256) {
    pa += (double)PART[i];
    tr += (double)QC[i*513];
    double q = (double)qmu[i]; mm += q*q;
    ld += (double)qlv[i*513];
  }
  double vals[4] = {pa, tr, mm, ld};
  double res[4];
  for (int t2 = 0; t2 < 4; ++t2) {
    sh[tid] = vals[t2]; __syncthreads();
    for (int s2 = 128; s2 > 0; s2 >>= 1) {
      if (tid < s2) sh[tid] += sh[tid+s2];
      __syncthreads();
    }
    res[t2] = sh[0]; __syncthreads();
  }
  if (tid == 0) {
    double n = 8192.0;
    double ell = res[0]/n;
    double kl = 0.5*(res[1] + res[2] - 512.0 - res[3])/n;
    out[0] = (float)(ell - kl);
  }
}

extern "C" void kernel_launch(void* const* d_in, const int* in_sizes, int n_in,
                              void* d_out, int out_size, void* d_ws, size_t ws_size,
                              hipStream_t stream) {
  (void)in_sizes; (void)n_in; (void)out_size; (void)ws_size;
  const float* X   = (const float*)d_in[0];
  const float* Y   = (const float*)d_in[1];
  const float* Z   = (const float*)d_in[2];
  const float* qmu = (const float*)d_in[3];
  const float* qlv = (const float*)d_in[4];
  const float* llv = (const float*)d_in[5];
  const float* ls  = (const float*)d_in[6];
  const float* os  = (const float*)d_in[7];
  float* ws = (float*)d_ws;
  float* out = (float*)d_out;

  k_prep<<<2048, 256, 0, stream>>>(Z, qlv, ls, os, ws);
  k_gemm_nt<<<dim3(8,8), 256, 0, stream>>>(ws+OFF_QS, ws+OFF_QS, ws+OFF_QC, JIT);
  k_dag<<<556, 256, 0, stream>>>(X, Y, Z, qmu, llv, ls, os, ws);
  k_final<<<1, 256, 0, stream>>>(qmu, qlv, ws, out);
}

// Round 9
// 456.843 us; speedup vs baseline: 2.8905x; 1.0152x over previous
//
#include <hip/hip_runtime.h>
#include <math.h>

#define MI 512
#define NPT 8192
#define JIT 1e-6f
#define LOG2PI 1.8378770664093453f

// ws float offsets
#define OFF_A     0         // 512x512 Kuu -> L (lower; diag blocks never read downstream)
#define OFF_LINV  262144    // 512x512 Linv^T (LT[r][c] = Linv[c][r]); upper region unused
#define OFF_QS    524288    // 512x512 q_sqrt
#define OFF_QC    786432    // 512x512 q_cov (symmetric)
#define OFF_DINV  1048576   // 8 x 64x64 diag-block inverses
#define OFF_PART  1081856   // 512 block partial ell sums
#define OFF_FLAGS 1082368   // 208 flags, each padded to 32 uints (128 B)
// flag ids (padded): fD=0..7, FL=8..71 (8+b*8+p), TFLG=72..135 (72+s*8+J),
//                    ROWC=136..143, GFLG=144..207 (144+b*8+p)
#define NFLAGS 208

#define FMA16(ACC,a0,a1,a2,a3,b0,b1,b2,b3) \
  ACC[0][0]+=a0*b0; ACC[0][1]+=a0*b1; ACC[0][2]+=a0*b2; ACC[0][3]+=a0*b3; \
  ACC[1][0]+=a1*b0; ACC[1][1]+=a1*b1; ACC[1][2]+=a1*b2; ACC[1][3]+=a1*b3; \
  ACC[2][0]+=a2*b0; ACC[2][1]+=a2*b1; ACC[2][2]+=a2*b2; ACC[2][3]+=a2*b3; \
  ACC[3][0]+=a3*b0; ACC[3][1]+=a3*b1; ACC[3][2]+=a3*b2; ACC[3][3]+=a3*b3;

__device__ __forceinline__ void wait_flag(unsigned* f, int tid) {
  if (tid == 0) {
    while (__hip_atomic_load(f, __ATOMIC_RELAXED, __HIP_MEMORY_SCOPE_AGENT) == 0)
      __builtin_amdgcn_s_sleep(2);
    __builtin_amdgcn_fence(__ATOMIC_ACQUIRE, "agent");
  }
  __syncthreads();
}
__device__ __forceinline__ void wait_count(unsigned* c, unsigned tgt, int tid) {
  if (tid == 0) {
    while (__hip_atomic_load(c, __ATOMIC_RELAXED, __HIP_MEMORY_SCOPE_AGENT) < tgt)
      __builtin_amdgcn_s_sleep(2);
    __builtin_amdgcn_fence(__ATOMIC_ACQUIRE, "agent");
  }
  __syncthreads();
}
__device__ __forceinline__ void raise_flag(unsigned* f, int tid) {
  __syncthreads();
  if (tid == 0) {
    __builtin_amdgcn_fence(__ATOMIC_RELEASE, "agent");
    __hip_atomic_store(f, 1u, __ATOMIC_RELAXED, __HIP_MEMORY_SCOPE_AGENT);
  }
}
__device__ __forceinline__ void publish_tile(unsigned* f, unsigned* cnt, int tid) {
  __syncthreads();
  if (tid == 0) {
    __builtin_amdgcn_fence(__ATOMIC_RELEASE, "agent");
    __hip_atomic_store(f, 1u, __ATOMIC_RELAXED, __HIP_MEMORY_SCOPE_AGENT);
    __hip_atomic_fetch_add(cnt, 1u, __ATOMIC_RELAXED, __HIP_MEMORY_SCOPE_AGENT);
  }
}

// ---------------------------------------------------------------- prep
__global__ __launch_bounds__(256) void k_prep(const float* __restrict__ Z,
    const float* __restrict__ qlv, const float* __restrict__ lsP,
    const float* __restrict__ osP, float* __restrict__ ws) {
  int u = blockIdx.x*256 + threadIdx.x;
  if (blockIdx.x < 26) {
    int fi = blockIdx.x*256 + threadIdx.x;
    if (fi < NFLAGS*32) ((unsigned*)(ws + OFF_FLAGS))[fi] = 0u;
  }
  float ls = lsP[0], os = osP[0];
  float ils2 = 1.0f/(ls*ls);
  if (u < MI*MI) {
    int i = u >> 9, j = u & 511;
    float4 a0 = *(const float4*)(Z + i*8);
    float4 a1 = *(const float4*)(Z + i*8 + 4);
    float4 b0 = *(const float4*)(Z + j*8);
    float4 b1 = *(const float4*)(Z + j*8 + 4);
    float d0=a0.x-b0.x, d1=a0.y-b0.y, d2=a0.z-b0.z, d3=a0.w-b0.w;
    float d4=a1.x-b1.x, d5=a1.y-b1.y, d6=a1.z-b1.z, d7=a1.w-b1.w;
    float sq = d0*d0+d1*d1+d2*d2+d3*d3+d4*d4+d5*d5+d6*d6+d7*d7;
    float v = os*__expf(-0.5f*ils2*sq);
    if (i==j) v += JIT;
    ws[OFF_A + u] = v;
  } else {
    int w2 = u - MI*MI;
    if (w2 < MI*MI) {
      int i = w2 >> 9, j = w2 & 511;
      ws[OFF_QS + w2] = (j <= i) ? __expf(0.5f*qlv[w2]) : 0.0f;
    }
  }
}

// ------------------------------------------------- O = X Y^T + adiag*I (K=512)
__global__ __launch_bounds__(256) void k_gemm_nt(const float* __restrict__ X,
    const float* __restrict__ Y, float* __restrict__ O, float adiag) {
  __shared__ float Xs[64][20], Ys[64][20];
  int tid = threadIdx.x;
  int bi = blockIdx.y, bj = blockIdx.x;
  int ty4 = (tid >> 4)*4, tx4 = (tid & 15)*4;
  int lrow = tid >> 2, lc4 = (tid & 3)*4;
  float acc[4][4] = {{0.f}};
  for (int kc = 0; kc < 512; kc += 16) {
    float4 xa = *(const float4*)(X + (bi*64+lrow)*512 + kc + lc4);
    float4 ya = *(const float4*)(Y + (bj*64+lrow)*512 + kc + lc4);
    Xs[lrow][lc4+0]=xa.x; Xs[lrow][lc4+1]=xa.y; Xs[lrow][lc4+2]=xa.z; Xs[lrow][lc4+3]=xa.w;
    Ys[lrow][lc4+0]=ya.x; Ys[lrow][lc4+1]=ya.y; Ys[lrow][lc4+2]=ya.z; Ys[lrow][lc4+3]=ya.w;
    __syncthreads();
    #pragma unroll
    for (int kk = 0; kk < 16; ++kk) {
      float a0=Xs[ty4+0][kk],a1=Xs[ty4+1][kk],a2=Xs[ty4+2][kk],a3=Xs[ty4+3][kk];
      float b0=Ys[tx4+0][kk],b1=Ys[tx4+1][kk],b2=Ys[tx4+2][kk],b3=Ys[tx4+3][kk];
      FMA16(acc,a0,a1,a2,a3,b0,b1,b2,b3)
    }
    __syncthreads();
  }
  #pragma unroll
  for (int u = 0; u < 4; ++u)
    #pragma unroll
    for (int v = 0; v < 4; ++v) {
      int gi = bi*64+ty4+u, gj = bj*64+tx4+v;
      float o = acc[u][v]; if (gi==gj) o += adiag;
      O[gi*512+gj] = o;
    }
}

// -------- fused DAG: chol(8) + linv(36) + gram-helpers(21) + main(512)
__global__ __launch_bounds__(256) void k_dag(const float* __restrict__ X,
    const float* __restrict__ Yv, const float* __restrict__ Z,
    const float* __restrict__ qmu, const float* __restrict__ llvP,
    const float* __restrict__ lsP, const float* __restrict__ osP,
    float* __restrict__ ws) {
  __shared__ float SH[13340];   // 53.36 KB -> 3 blocks/CU
  float* A    = ws + OFF_A;
  float* LT   = ws + OFF_LINV;
  const float* QC = ws + OFF_QC;
  float* DINV = ws + OFF_DINV;
  float* PART = ws + OFF_PART;
  unsigned* FB = (unsigned*)(ws + OFF_FLAGS);
  #define FLA(i) (FB + (i)*32)
  int bid = blockIdx.x, tid = threadIdx.x;
  int ty4 = (tid >> 4)*4, tx4 = (tid & 15)*4;

  // ================= CHOL path ==============
  if (bid < 8) {
    __builtin_amdgcn_s_setprio(3);
    int b = bid, Rb = b*64;
    float* Dg = SH;            // [64][65] running diag tile
    float* Sa = SH + 4160;     // Dinv staging / assembly
    float* Sb = SH + 8320;     // G / Lsub staging
    float* TMP = SH + 12480;   // 816 floats
    for (int e = tid; e < 4096; e += 256)
      Dg[(e>>6)*65 + (e&63)] = A[(Rb + (e>>6))*512 + Rb + (e&63)];

    for (int p = 0; p < b; ++p) {
      if (p > 0) wait_flag(FLA(144 + b*8 + p), tid);   // helper wrote G into A(b,p)
      wait_flag(FLA(p), tid);                          // fD[p]
      for (int e = tid; e < 4096; e += 256) {
        Sa[(e>>6)*65 + (e&63)] = DINV[p*4096 + e];
        Sb[(e>>6)*65 + (e&63)] = A[(Rb + (e>>6))*512 + p*64 + (e&63)];
      }
      __syncthreads();
      // TRSM: Lsub = G * Dinv_p^T
      float acc2[4][4] = {{0.f}};
      for (int m = 0; m < 64; ++m) {
        float a0=Sb[(ty4+0)*65+m],a1=Sb[(ty4+1)*65+m],a2=Sb[(ty4+2)*65+m],a3=Sb[(ty4+3)*65+m];
        float b0=Sa[(tx4+0)*65+m],b1=Sa[(tx4+1)*65+m],b2=Sa[(tx4+2)*65+m],b3=Sa[(tx4+3)*65+m];
        FMA16(acc2,a0,a1,a2,a3,b0,b1,b2,b3)
      }
      __syncthreads();
      #pragma unroll
      for (int u = 0; u < 4; ++u)
        #pragma unroll
        for (int v = 0; v < 4; ++v) {
          Sb[(ty4+u)*65 + tx4+v] = acc2[u][v];
          A[(Rb+ty4+u)*512 + p*64 + tx4+v] = acc2[u][v];
        }
      raise_flag(FLA(8 + b*8 + p), tid);
      // SYRK: Dg -= Lsub Lsub^T
      float c2[4][4] = {{0.f}};
      for (int m = 0; m < 64; ++m) {
        float a0=Sb[(ty4+0)*65+m],a1=Sb[(ty4+1)*65+m],a2=Sb[(ty4+2)*65+m],a3=Sb[(ty4+3)*65+m];
        float b0=Sb[(tx4+0)*65+m],b1=Sb[(tx4+1)*65+m],b2=Sb[(tx4+2)*65+m],b3=Sb[(tx4+3)*65+m];
        FMA16(c2,a0,a1,a2,a3,b0,b1,b2,b3)
      }
      #pragma unroll
      for (int u = 0; u < 4; ++u)
        #pragma unroll
        for (int v = 0; v < 4; ++v)
          Dg[(ty4+u)*65 + tx4+v] -= c2[u][v];
    }
    __syncthreads();

    // factor 64x64 Dg via 16-wide sub-panels; Dinv assembled into Sa
    for (int e = tid; e < 4096; e += 256) Sa[(e>>6)*65 + (e&63)] = 0.0f;
    __syncthreads();
    for (int t = 0; t < 4; ++t) {
      const int c0 = t*16;
      if (tid < 16) {
        float a[16];
        #pragma unroll
        for (int j = 0; j < 16; ++j) a[j] = Dg[(c0+tid)*65 + c0 + j];
        float rr = 0.f;
        #pragma unroll
        for (int j = 0; j < 16; ++j) {
          float d = __shfl(a[j], j);
          float r = rsqrtf(d);
          r = r*(1.5f - 0.5f*d*r*r);
          if (tid == j) rr = r;
          a[j] *= r;
          #pragma unroll
          for (int k = j+1; k < 16; ++k)
            a[k] -= a[j]*__shfl(a[j], k);
        }
        #pragma unroll
        for (int j = 0; j < 16; ++j)
          Dg[(c0+tid)*65 + c0 + j] = (j <= tid) ? a[j] : 0.0f;
        float v[16];
        #pragma unroll
        for (int i = 0; i < 16; ++i) {
          float s = (tid == i) ? 1.0f : 0.0f;
          #pragma unroll
          for (int k = 0; k < i; ++k)
            s -= Dg[(c0+i)*65 + c0 + k]*v[k];
          v[i] = s * __shfl(rr, i);
        }
        #pragma unroll
        for (int i = 0; i < 16; ++i)
          Sa[(c0+i)*65 + c0 + tid] = v[i];
      }
      __syncthreads();
      if (t < 3) {
        const int cnt = 48 - c0;
        const int r0 = c0 + 16;
        float res[3];
        int nout = cnt*16, idx = 0;
        for (int e = tid; e < nout; e += 256, ++idx) {
          int r = r0 + (e >> 4), j = e & 15;
          float s = 0.f;
          #pragma unroll
          for (int m = 0; m < 16; ++m)
            s += Dg[r*65 + c0 + m]*Sa[(c0+j)*65 + c0 + m];
          res[idx] = s;
        }
        __syncthreads();
        idx = 0;
        for (int e = tid; e < nout; e += 256, ++idx)
          Dg[(r0 + (e >> 4))*65 + c0 + (e & 15)] = res[idx];
        __syncthreads();
        for (int e = tid; e < cnt*cnt; e += 256) {
          int r = r0 + e/cnt, c = r0 + e%cnt;
          float s = 0.f;
          #pragma unroll
          for (int m = 0; m < 16; ++m)
            s += Dg[r*65 + c0 + m]*Dg[c*65 + c0 + m];
          Dg[r*65 + c] -= s;
        }
        __syncthreads();
      }
    }
    for (int d = 1; d < 4; ++d) {
      int nout = (4-d)*256;
      for (int e = tid; e < nout; e += 256) {
        int bs = e >> 8, I = bs, J = I + d;
        int i = (e >> 4) & 15, c = e & 15;
        float s = 0.f;
        for (int k = I; k < J; ++k) {
          #pragma unroll
          for (int m = 0; m < 16; ++m)
            s += Dg[(J*16+i)*65 + k*16+m]*Sa[(k*16+m)*65 + I*16+c];
        }
        TMP[bs*272 + i*17 + c] = s;
      }
      __syncthreads();
      for (int e = tid; e < nout; e += 256) {
        int bs = e >> 8, I = bs, J = I + d;
        int i = (e >> 4) & 15, c = e & 15;
        float s = 0.f;
        #pragma unroll
        for (int m = 0; m < 16; ++m)
          s += Sa[(J*16+i)*65 + J*16+m]*TMP[bs*272 + m*17 + c];
        Sa[(J*16+i)*65 + I*16+c] = -s;
      }
      __syncthreads();
    }
    for (int e = tid; e < 4096; e += 256)
      DINV[b*4096 + e] = Sa[(e>>6)*65 + (e&63)];
    raise_flag(FLA(b), tid);
    return;
  }

  // ================= LINV path (36 lower-tri tiles) ======================
  if (bid < 44) {
    __builtin_amdgcn_s_setprio(2);
    int t = bid - 8;
    int s = 0, rem = t;
    while (rem >= s+1) { rem -= (s+1); ++s; }
    int J = rem;
    if (s == J) {
      wait_flag(FLA(s), tid);
      for (int e = tid; e < 4096; e += 256) {
        int i = e >> 6, j = e & 63;
        LT[(64*s+j)*512 + 64*s + i] = DINV[s*4096 + e];
      }
      publish_tile(FLA(72 + s*8 + J), FLA(136 + s), tid);
      return;
    }
    float* Ls = SH;
    float* Vs = SH + 4160;
    float* T  = SH + 8320;
    float acc[4][4] = {{0.f}};
    for (int k = J; k < s; ++k) {
      wait_flag(FLA(72 + k*8 + J), tid);
      wait_flag(FLA(8 + s*8 + k), tid);
      for (int e = tid; e < 1024; e += 256) {
        int row = e >> 4, m4 = (e & 15)*4;
        float4 a = *(const float4*)(A + (64*s+row)*512 + 64*k + m4);
        Ls[row*65+m4+0]=a.x; Ls[row*65+m4+1]=a.y; Ls[row*65+m4+2]=a.z; Ls[row*65+m4+3]=a.w;
        float4 v = *(const float4*)(LT + (64*J+row)*512 + 64*k + m4);
        Vs[(m4+0)*65+row]=v.x; Vs[(m4+1)*65+row]=v.y; Vs[(m4+2)*65+row]=v.z; Vs[(m4+3)*65+row]=v.w;
      }
      __syncthreads();
      for (int m = 0; m < 64; ++m) {
        float a0=Ls[(ty4+0)*65+m],a1=Ls[(ty4+1)*65+m],a2=Ls[(ty4+2)*65+m],a3=Ls[(ty4+3)*65+m];
        float b0=Vs[m*65+tx4+0],b1=Vs[m*65+tx4+1],b2=Vs[m*65+tx4+2],b3=Vs[m*65+tx4+3];
        FMA16(acc,a0,a1,a2,a3,b0,b1,b2,b3)
      }
      __syncthreads();
    }
    wait_flag(FLA(s), tid);
    #pragma unroll
    for (int u = 0; u < 4; ++u)
      #pragma unroll
      for (int v = 0; v < 4; ++v)
        T[(ty4+u)*65 + tx4+v] = acc[u][v];
    for (int e = tid; e < 4096; e += 256) Ls[(e>>6)*65 + (e&63)] = DINV[s*4096 + e];
    __syncthreads();
    float acc2[4][4] = {{0.f}};
    for (int m = 0; m < 64; ++m) {
      float a0=Ls[(ty4+0)*65+m],a1=Ls[(ty4+1)*65+m],a2=Ls[(ty4+2)*65+m],a3=Ls[(ty4+3)*65+m];
      float b0=T[m*65+tx4+0],b1=T[m*65+tx4+1],b2=T[m*65+tx4+2],b3=T[m*65+tx4+3];
      FMA16(acc2,a0,a1,a2,a3,b0,b1,b2,b3)
    }
    #pragma unroll
    for (int u = 0; u < 4; ++u)
      #pragma unroll
      for (int v = 0; v < 4; ++v)
        LT[(64*J+tx4+v)*512 + 64*s+ty4+u] = -acc2[u][v];
    publish_tile(FLA(72 + s*8 + J), FLA(136 + s), tid);
    return;
  }

  // ================= GRAM helpers (21 blocks) ============================
  if (bid < 65) {
    __builtin_amdgcn_s_setprio(2);
    int hid = bid - 44;
    int b = 2, rem = hid;
    while (rem >= b-1) { rem -= (b-1); ++b; }
    int p = rem + 1;                       // 1 <= p < b
    float* Sa = SH;                        // [64][65] Lsub(b,pp)
    float* Sb = SH + 4160;                 // [64][65] Lsub(p,pp)
    float gacc[4][4] = {{0.f}};
    for (int pp = 0; pp < p; ++pp) {
      wait_flag(FLA(8 + b*8 + pp), tid);
      wait_flag(FLA(8 + p*8 + pp), tid);
      for (int e = tid; e < 4096; e += 256) {
        int row = e>>6, col = e&63;
        Sa[row*65+col] = A[(b*64+row)*512 + pp*64 + col];
        Sb[row*65+col] = A[(p*64+row)*512 + pp*64 + col];
      }
      __syncthreads();
      for (int m = 0; m < 64; ++m) {
        float a0=Sa[(ty4+0)*65+m],a1=Sa[(ty4+1)*65+m],a2=Sa[(ty4+2)*65+m],a3=Sa[(ty4+3)*65+m];
        float b0=Sb[(tx4+0)*65+m],b1=Sb[(tx4+1)*65+m],b2=Sb[(tx4+2)*65+m],b3=Sb[(tx4+3)*65+m];
        FMA16(gacc,a0,a1,a2,a3,b0,b1,b2,b3)
      }
      __syncthreads();
    }
    // A(b,p) -= gram  (in place; original Kuu values, static since k_prep)
    #pragma unroll
    for (int u = 0; u < 4; ++u)
      #pragma unroll
      for (int v = 0; v < 4; ++v)
        A[(b*64+ty4+u)*512 + p*64 + tx4+v] -= gacc[u][v];
    raise_flag(FLA(144 + b*8 + p), tid);
    return;
  }

  // ================= MAIN path (512 blocks, slab-gated) ==================
  {
    int B = bid - 65;
    float* KL  = SH;            // 8192: k[c][pt] stride 16
    float* Lst = SH + 8192;     // 1280: l-slab staging
    float* RD  = SH + 9472;     // 2176
    float* qsh = SH + 11648;    // 512
    float* Xs  = SH + 12160;    // 128
    float* pmv = SH + 12288;    // 16
    float* lsqv= SH + 12304;    // 16
    float* elli= SH + 12320;    // 16
    float ls = lsP[0], os = osP[0], llv = llvP[0];
    float ils2 = 1.0f/(ls*ls);
    if (tid < 128) { int pp = tid>>3, d = tid&7; Xs[pp*8+d] = X[(B*16+pp)*8 + d]; }
    qsh[tid] = qmu[tid]; qsh[tid+256] = qmu[tid+256];
    __syncthreads();
    for (int e = tid; e < 8192; e += 256) {
      int cc = e >> 4, pp = e & 15;
      float4 z0 = *(const float4*)(Z + cc*8);
      float4 z1 = *(const float4*)(Z + cc*8 + 4);
      float d0=z0.x-Xs[pp*8+0], d1=z0.y-Xs[pp*8+1], d2=z0.z-Xs[pp*8+2], d3=z0.w-Xs[pp*8+3];
      float d4=z1.x-Xs[pp*8+4], d5=z1.y-Xs[pp*8+5], d6=z1.z-Xs[pp*8+6], d7=z1.w-Xs[pp*8+7];
      float sq = d0*d0+d1*d1+d2*d2+d3*d3+d4*d4+d5*d5+d6*d6+d7*d7;
      KL[e] = os*__expf(-0.5f*ils2*sq);
    }
    __syncthreads();
    int rq = tid >> 2, rq4 = rq*4, pq4 = (tid & 3)*4;
    int sl = tid >> 6;
    float ua0[4][4] = {{0.f}}, ua1[4][4] = {{0.f}};
    float pmp[4] = {0.f,0.f,0.f,0.f}, lsp[4] = {0.f,0.f,0.f,0.f};
    for (int s = 0; s < 8; ++s) {
      wait_count(FLA(136 + s), (unsigned)(s+1), tid);
      int active = (s < 4) ? (sl == s) : (sl == s-4);
      if (active) {
        float acc[4][4] = {{0.f}};
        const float* Lbase = LT + ((s < 4) ? rq4 : (256 + rq4));
        int clen = 64*(s+1);
        #pragma unroll 4
        for (int c = 0; c < clen; ++c) {
          float4 kv = *(const float4*)&KL[c*16 + pq4];
          float4 l0 = *(const float4*)(Lbase + c*512);
          FMA16(acc, l0.x,l0.y,l0.z,l0.w, kv.x,kv.y,kv.z,kv.w)
        }
        int rg = (s < 4) ? rq4 : (256 + rq4);
        int rl4 = rg - s*64;
        #pragma unroll
        for (int u = 0; u < 4; ++u) {
          float q = qsh[rg + u];
          #pragma unroll
          for (int v = 0; v < 4; ++v) {
            pmp[v] += acc[u][v]*q;
            lsp[v] += acc[u][v]*acc[u][v];
            Lst[(rl4+u)*20 + pq4+v] = acc[u][v];
          }
        }
      }
      __syncthreads();
      for (int cl = 0; cl < 64; ++cl) {
        float4 kv = *(const float4*)&Lst[cl*20 + pq4];
        float4 q0 = *(const float4*)(QC + (64*s+cl)*512 + rq4);
        float4 q1 = *(const float4*)(QC + (64*s+cl)*512 + 256 + rq4);
        FMA16(ua0, q0.x,q0.y,q0.z,q0.w, kv.x,kv.y,kv.z,kv.w)
        FMA16(ua1, q1.x,q1.y,q1.z,q1.w, kv.x,kv.y,kv.z,kv.w)
      }
      __syncthreads();
    }
    #pragma unroll
    for (int v = 0; v < 4; ++v) {
      RD[rq*17 + pq4+v] = pmp[v];
      RD[1088 + rq*17 + pq4+v] = lsp[v];
    }
    __syncthreads();
    if (tid < 16) {
      float a = 0.f, b2 = 0.f;
      for (int r2 = 0; r2 < 64; ++r2) { a += RD[r2*17+tid]; b2 += RD[1088+r2*17+tid]; }
      pmv[tid] = a; lsqv[tid] = b2;
    }
    __syncthreads();
    float usq[4] = {0.f,0.f,0.f,0.f};
    #pragma unroll
    for (int u = 0; u < 4; ++u)
      #pragma unroll
      for (int v = 0; v < 4; ++v)
        usq[v] += ua0[u][v]*ua0[u][v] + ua1[u][v]*ua1[u][v];
    #pragma unroll
    for (int v = 0; v < 4; ++v) RD[rq*17 + pq4+v] = usq[v];
    __syncthreads();
    if (tid < 16) {
      float us = 0.f;
      for (int r2 = 0; r2 < 64; ++r2) us += RD[r2*17+tid];
      int gi = B*16 + tid;
      float diff = Yv[gi] - pmv[tid];
      float diagc = os + us - lsqv[tid];
      float iss = __expf(-llv);
      elli[tid] = -0.5f*((diff*diff + diagc)*iss + (LOG2PI + llv));
    }
    __syncthreads();
    if (tid == 0) {
      float sum = 0.f;
      #pragma unroll
      for (int i2 = 0; i2 < 16; ++i2) sum += elli[i2];
      PART[B] = sum;
    }
  }
}

// --------------------- final scalar
__global__ __launch_bounds__(256) void k_final(const float* __restrict__ qmu,
    const float* __restrict__ qlv, float* __restrict__ ws, float* __restrict__ out) {
  __shared__ double sh[256];
  int tid = threadIdx.x;
  const float* QC = ws + OFF_QC;
  const float* PART = ws + OFF_PART;
  double pa = 0.0, tr = 0.0, mm = 0.0, ld = 0.0;
  for (int i = tid; i < 512; i += 256) {
    pa += (double)PART[i];
    tr += (double)QC[i*513];
    double q = (double)qmu[i]; mm += q*q;
    ld += (double)qlv[i*513];
  }
  double vals[4] = {pa, tr, mm, ld};
  double res[4];
  for (int t2 = 0; t2 < 4; ++t2) {
    sh[tid] = vals[t2]; __syncthreads();
    for (int s2 = 128; s2 > 0; s2 >>= 1) {
      if (tid < s2) sh[tid] += sh[tid+s2];
      __syncthreads();
    }
    res[t2] = sh[0]; __syncthreads();
  }
  if (tid == 0) {
    double n = 8192.0;
    double ell = res[0]/n;
    double kl = 0.5*(res[1] + res[2] - 512.0 - res[3])/n;
    out[0] = (float)(ell - kl);
  }
}

extern "C" void kernel_launch(void* const* d_in, const int* in_sizes, int n_in,
                              void* d_out, int out_size, void* d_ws, size_t ws_size,
                              hipStream_t stream) {
  (void)in_sizes; (void)n_in; (void)out_size; (void)ws_size;
  const float* X   = (const float*)d_in[0];
  const float* Y   = (const float*)d_in[1];
  const float* Z   = (const float*)d_in[2];
  const float* qmu = (const float*)d_in[3];
  const float* qlv = (const float*)d_in[4];
  const float* llv = (const float*)d_in[5];
  const float* ls  = (const float*)d_in[6];
  const float* os  = (const float*)d_in[7];
  float* ws = (float*)d_ws;
  float* out = (float*)d_out;

  k_prep<<<2048, 256, 0, stream>>>(Z, qlv, ls, os, ws);
  k_gemm_nt<<<dim3(8,8), 256, 0, stream>>>(ws+OFF_QS, ws+OFF_QS, ws+OFF_QC, JIT);
  k_dag<<<577, 256, 0, stream>>>(X, Y, Z, qmu, llv, ls, os, ws);
  k_final<<<1, 256, 0, stream>>>(qmu, qlv, ws, out);
}